// Round 13
// baseline (727.221 us; speedup 1.0000x reference)
//
#include <hip/hip_runtime.h>
#include <hip/hip_bf16.h>

typedef __bf16 bf16x8 __attribute__((ext_vector_type(8)));
typedef float f32x4 __attribute__((ext_vector_type(4)));

#define MFMA_BF16(a,b,c) __builtin_amdgcn_mfma_f32_16x16x32_bf16(a,b,c,0,0,0)

#define GLOAD16(g, l) __builtin_amdgcn_global_load_lds( \
    (const __attribute__((address_space(1))) unsigned int*)(g), \
    (__attribute__((address_space(3))) unsigned int*)(l), 16, 0, 0)

__device__ __forceinline__ unsigned short f2bf(float f) {
  unsigned u = __builtin_bit_cast(unsigned, f);
  return (unsigned short)((u + 0x7FFFu + ((u >> 16) & 1u)) >> 16);
}

// -- merged pre-pass: hidden convert + Wqkv transpose (+ optional Wo transpose)
__global__ __launch_bounds__(256)
void prep_merged(const float* __restrict__ hidden, unsigned short* __restrict__ hiddenB,
                 const float* __restrict__ Wqkv, unsigned short* __restrict__ WqkvT,
                 const float* __restrict__ Wo, unsigned short* __restrict__ WoT) {
  __shared__ float tl[64][65];
  const int id = blockIdx.x;
  const bool hasWo = (WoT != nullptr);
  if (id < 12288) {
    // transpose-convert Wqkv [4096][12288] -> WqkvT [12288][4096]
    const int n0 = (id % 192) * 64, k0 = (id / 192) * 64;
    const int K = 4096, N = 12288;
    const int tr = threadIdx.x >> 4;
    const int tc4 = (threadIdx.x & 15) * 4;
    for (int i = 0; i < 4; ++i) {
      int r = tr + i*16;
      float4 v = *(const float4*)(Wqkv + (size_t)(k0 + r)*N + n0 + tc4);
      tl[r][tc4+0] = v.x; tl[r][tc4+1] = v.y;
      tl[r][tc4+2] = v.z; tl[r][tc4+3] = v.w;
    }
    __syncthreads();
    for (int i = 0; i < 4; ++i) {
      int nr = tr + i*16;
      short4 h;
      h.x = (short)f2bf(tl[tc4+0][nr]);
      h.y = (short)f2bf(tl[tc4+1][nr]);
      h.z = (short)f2bf(tl[tc4+2][nr]);
      h.w = (short)f2bf(tl[tc4+3][nr]);
      *(short4*)(WqkvT + (size_t)(n0 + nr)*K + k0 + tc4) = h;
    }
  } else if (hasWo && id < 16384) {
    // transpose-convert Wo [4096][4096] -> WoT [4096][4096]
    const int id2 = id - 12288;
    const int n0 = (id2 & 63) * 64, k0 = (id2 >> 6) * 64;
    const int K = 4096, N = 4096;
    const int tr = threadIdx.x >> 4;
    const int tc4 = (threadIdx.x & 15) * 4;
    for (int i = 0; i < 4; ++i) {
      int r = tr + i*16;
      float4 v = *(const float4*)(Wo + (size_t)(k0 + r)*N + n0 + tc4);
      tl[r][tc4+0] = v.x; tl[r][tc4+1] = v.y;
      tl[r][tc4+2] = v.z; tl[r][tc4+3] = v.w;
    }
    __syncthreads();
    for (int i = 0; i < 4; ++i) {
      int nr = tr + i*16;
      short4 h;
      h.x = (short)f2bf(tl[tc4+0][nr]);
      h.y = (short)f2bf(tl[tc4+1][nr]);
      h.z = (short)f2bf(tl[tc4+2][nr]);
      h.w = (short)f2bf(tl[tc4+3][nr]);
      *(short4*)(WoT + (size_t)(n0 + nr)*K + k0 + tc4) = h;
    }
  } else {
    // convert hidden f32 -> bf16, 8 elems/thread/iter
    const int cbase = hasWo ? 16384 : 12288;
    const int n8 = 4096*4096/8;
    int i = (id - cbase) * 256 + threadIdx.x;
    const int stride = 2048 * 256;
    for (; i < n8; i += stride) {
      float4 a = ((const float4*)hidden)[i*2];
      float4 b = ((const float4*)hidden)[i*2 + 1];
      short4 h0, h1;
      h0.x = (short)f2bf(a.x); h0.y = (short)f2bf(a.y);
      h0.z = (short)f2bf(a.z); h0.w = (short)f2bf(a.w);
      h1.x = (short)f2bf(b.x); h1.y = (short)f2bf(b.y);
      h1.z = (short)f2bf(b.z); h1.w = (short)f2bf(b.w);
      ((short4*)hiddenB)[i*2] = h0;
      ((short4*)hiddenB)[i*2 + 1] = h1;
    }
  }
}

// ---------------- pre-pass: W [K][N] f32 -> Wt [N][K] bf16 (fallback use) -----
__global__ __launch_bounds__(256)
void transpose_convert(const float* __restrict__ W, unsigned short* __restrict__ Wt,
                       int K, int N) {
  __shared__ float tl[64][65];
  const int k0 = blockIdx.y * 64, n0 = blockIdx.x * 64;
  const int tr = threadIdx.x >> 4;
  const int tc4 = (threadIdx.x & 15) * 4;
  for (int i = 0; i < 4; ++i) {
    int r = tr + i*16;
    float4 v = *(const float4*)(W + (size_t)(k0 + r)*N + n0 + tc4);
    tl[r][tc4+0] = v.x; tl[r][tc4+1] = v.y;
    tl[r][tc4+2] = v.z; tl[r][tc4+3] = v.w;
  }
  __syncthreads();
  for (int i = 0; i < 4; ++i) {
    int nr = tr + i*16;
    short4 h;
    h.x = (short)f2bf(tl[tc4+0][nr]);
    h.y = (short)f2bf(tl[tc4+1][nr]);
    h.z = (short)f2bf(tl[tc4+2][nr]);
    h.w = (short)f2bf(tl[tc4+3][nr]);
    *(short4*)(Wt + (size_t)(n0 + nr)*K + k0 + tc4) = h;
  }
}

// ------- pre-pass: V region of qkv -> Vt[bh][d][s] bf16 (non-vfuse fallback) --
__global__ __launch_bounds__(256)
void transpose_v(const unsigned short* __restrict__ qkv,
                 unsigned short* __restrict__ Vt) {
  __shared__ unsigned short tl[64][68];
  const int bh = blockIdx.z;
  const int s0 = blockIdx.x * 64;
  const int d0 = blockIdx.y * 64;
  const int b = bh >> 4, h = bh & 15;
  const int tr = threadIdx.x >> 4;
  const int tc = (threadIdx.x & 15) * 4;
  const unsigned short* src = qkv + ((size_t)(b*2048 + s0))*12288 + 8192 + h*256 + d0;
  for (int i = 0; i < 4; ++i) {
    int s = tr + i*16;
    *(short4*)&tl[s][tc] = *(const short4*)(src + (size_t)s*12288 + tc);
  }
  __syncthreads();
  unsigned short* dst = Vt + ((size_t)bh*256 + d0)*2048 + s0;
  for (int i = 0; i < 4; ++i) {
    int d = tr + i*16;
    short4 h4;
    h4.x = (short)tl[tc+0][d];
    h4.y = (short)tl[tc+1][d];
    h4.z = (short)tl[tc+2][d];
    h4.w = (short)tl[tc+3][d];
    *(short4*)(dst + (size_t)d*2048 + tc) = h4;
  }
}

// -- 256x256 GEMM, BK=64, 8 waves, m201-style 8-phase / 2-K-tile iteration -----
// r11/r12 schedule verbatim. Block order is COLUMN-BAND MAJOR (by=wg%16,
// bx=wg/16): each XCD's 32 concurrent blocks share ~2 B-panels (4 MB = XCD L2)
// so B is HBM-fetched ~once; A (33.5 MB) streams but L3-resident.
template<bool ROPE, bool OUT_BF16, bool VFUSE>
__global__ __launch_bounds__(512, 2)
void gemm256p(const unsigned short* __restrict__ A,
              const unsigned short* __restrict__ Bt,
              const int* __restrict__ pos,
              void* __restrict__ Cp, int N, int K, int nrow,
              unsigned short* __restrict__ Vt)
{
  __shared__ __align__(16) unsigned short L[2][4][8192];   // 128 KiB
  const int tid = threadIdx.x, lane = tid & 63, w = tid >> 6;
  const int wr = w >> 2, wc = w & 3;
  const int nwg = gridDim.x;
  int wg = blockIdx.x;
  if ((nwg & 7) == 0) wg = (wg & 7) * (nwg >> 3) + (wg >> 3);   // XCD swizzle
  const int by = wg % nrow, bx = wg / nrow;   // column-band major
  const int row0 = by * 256, col0 = bx * 256;

  const int crow = lane & 15, g = lane >> 4;
  const int xo = (crow & 7) << 4;           // read-side XOR (bytes)
  const int rB0 = (wc & 1) * 64;
  const unsigned bo = (unsigned)((tid >> 3) * K + (((tid & 7) ^ ((tid >> 3) & 7)) * 8));
  const int nt = K >> 6;

#define STG_A(T,BUF,H,RLO) do { if ((T) < nt)                                   \
    GLOAD16(A + (unsigned)((row0 + (H)*128 + (RLO))*K) + bo + (unsigned)(T)*64u,\
            &L[BUF][H][(RLO)*64 + tid*8]); } while (0)
#define STG_B(T,BUF,H,RLO) do { if ((T) < nt)                                   \
    GLOAD16(Bt + (unsigned)((col0 + (H)*128 + (RLO))*K) + bo + (unsigned)(T)*64u,\
            &L[BUF][2+(H)][(RLO)*64 + tid*8]); } while (0)

#define RD_ALO(BUF) _Pragma("unroll") for (int m = 0; m < 4; ++m)               \
    _Pragma("unroll") for (int kk = 0; kk < 2; ++kk)                            \
      pAlo[m][kk] = *(const bf16x8*)((const char*)&L[BUF][wr][0] +              \
                     (m*16 + crow)*128 + ((((kk*4+g)<<4)) ^ xo));
#define RD_AHI(BUF) _Pragma("unroll") for (int m = 0; m < 4; ++m)               \
    _Pragma("unroll") for (int kk = 0; kk < 2; ++kk)                            \
      pAhi[m][kk] = *(const bf16x8*)((const char*)&L[BUF][wr][0] +              \
                     (64 + m*16 + crow)*128 + ((((kk*4+g)<<4)) ^ xo));
#define RD_B0(BUF) _Pragma("unroll") for (int n = 0; n < 2; ++n)                \
    _Pragma("unroll") for (int kk = 0; kk < 2; ++kk)                            \
      pB0[n][kk] = *(const bf16x8*)((const char*)&L[BUF][2+(wc>>1)][0] +        \
                    (rB0 + n*16 + crow)*128 + ((((kk*4+g)<<4)) ^ xo));
#define RD_B1(BUF) _Pragma("unroll") for (int n = 0; n < 2; ++n)                \
    _Pragma("unroll") for (int kk = 0; kk < 2; ++kk)                            \
      pB1[n][kk] = *(const bf16x8*)((const char*)&L[BUF][2+(wc>>1)][0] +        \
                    (rB0 + 32 + n*16 + crow)*128 + ((((kk*4+g)<<4)) ^ xo));
#define Q00 _Pragma("unroll") for (int kk = 0; kk < 2; ++kk)                    \
    _Pragma("unroll") for (int m = 0; m < 4; ++m)                               \
    _Pragma("unroll") for (int n = 0; n < 2; ++n)                               \
      acc[m][n] = MFMA_BF16(pAlo[m][kk], pB0[n][kk], acc[m][n]);
#define Q01 _Pragma("unroll") for (int kk = 0; kk < 2; ++kk)                    \
    _Pragma("unroll") for (int m = 0; m < 4; ++m)                               \
    _Pragma("unroll") for (int n = 0; n < 2; ++n)                               \
      acc[m][2+n] = MFMA_BF16(pAlo[m][kk], pB1[n][kk], acc[m][2+n]);
#define Q10 _Pragma("unroll") for (int kk = 0; kk < 2; ++kk)                    \
    _Pragma("unroll") for (int m = 0; m < 4; ++m)                               \
    _Pragma("unroll") for (int n = 0; n < 2; ++n)                               \
      acc[4+m][n] = MFMA_BF16(pAhi[m][kk], pB0[n][kk], acc[4+m][n]);
#define Q11 _Pragma("unroll") for (int kk = 0; kk < 2; ++kk)                    \
    _Pragma("unroll") for (int m = 0; m < 4; ++m)                               \
    _Pragma("unroll") for (int n = 0; n < 2; ++n)                               \
      acc[4+m][2+n] = MFMA_BF16(pAhi[m][kk], pB1[n][kk], acc[4+m][2+n]);
#define BAR __builtin_amdgcn_s_barrier()
#define LGKM0 asm volatile("s_waitcnt lgkmcnt(0)" ::: "memory")
#define LGKM8 asm volatile("s_waitcnt lgkmcnt(8)" ::: "memory")
#define PRIO1 __builtin_amdgcn_s_setprio(1)
#define PRIO0 __builtin_amdgcn_s_setprio(0)

  f32x4 acc[8][4] = {};
  // ---- prologue: tile0 complete (8 loads) + tile1 minus A-hi (6 loads) ----
  STG_A(0,0,0,0);  STG_A(0,0,0,64); STG_A(0,0,1,0);  STG_A(0,0,1,64);
  STG_B(0,0,0,0);  STG_B(0,0,0,64); STG_B(0,0,1,0);  STG_B(0,0,1,64);
  STG_A(1,1,0,0);  STG_A(1,1,1,0);
  STG_B(1,1,0,0);  STG_B(1,1,0,64); STG_B(1,1,1,0);  STG_B(1,1,1,64);
  asm volatile("s_waitcnt vmcnt(6)" ::: "memory");   // tile 0 resident
  BAR;

  const int nI = nt >> 1;
  for (int i = 0; i < nI; ++i) {
    const int t = 2*i;
    const bool last = (i == nI - 1);
    bf16x8 pAlo[4][2], pAhi[4][2], pB0[2][2], pB1[2][2];

    // ======== tile t (buf0) ========
    RD_ALO(0); RD_B0(0);
    STG_A(t+1, 1, 0, 64); STG_A(t+1, 1, 1, 64);
    LGKM8;
    BAR; LGKM0; PRIO1; Q00; PRIO0; BAR;
    RD_B1(0);
    STG_A(t+2, 0, 0, 0); STG_A(t+2, 0, 1, 0);
    BAR; LGKM0; PRIO1; Q01; PRIO0; BAR;
    RD_AHI(0);
    STG_B(t+2, 0, 0, 0); STG_B(t+2, 0, 0, 64);
    BAR; LGKM0; PRIO1; Q10; PRIO0; BAR;
    STG_B(t+2, 0, 1, 0); STG_B(t+2, 0, 1, 64);
    PRIO1; Q11; PRIO0;
    if (!last) asm volatile("s_waitcnt vmcnt(6)" ::: "memory");
    else       asm volatile("s_waitcnt vmcnt(0)" ::: "memory");
    BAR;

    // ======== tile t+1 (buf1) ========
    RD_ALO(1); RD_B0(1);
    STG_A(t+2, 0, 0, 64); STG_A(t+2, 0, 1, 64);
    LGKM8;
    BAR; LGKM0; PRIO1; Q00; PRIO0; BAR;
    RD_B1(1);
    STG_A(t+3, 1, 0, 0); STG_A(t+3, 1, 1, 0);
    BAR; LGKM0; PRIO1; Q01; PRIO0; BAR;
    RD_AHI(1);
    STG_B(t+3, 1, 0, 0); STG_B(t+3, 1, 0, 64);
    BAR; LGKM0; PRIO1; Q10; PRIO0; BAR;
    STG_B(t+3, 1, 1, 0); STG_B(t+3, 1, 1, 64);
    PRIO1; Q11; PRIO0;
    if (!last) asm volatile("s_waitcnt vmcnt(6)" ::: "memory");
    else       asm volatile("s_waitcnt vmcnt(0)" ::: "memory");
    BAR;
  }
#undef STG_A
#undef STG_B
#undef RD_ALO
#undef RD_AHI
#undef RD_B0
#undef RD_B1
#undef Q00
#undef Q01
#undef Q10
#undef Q11
#undef BAR
#undef LGKM0
#undef LGKM8
#undef PRIO1
#undef PRIO0

  // ---- fused-Vt epilogue for V-region blocks (block-uniform branch) ----
  if (VFUSE && ROPE && col0 >= 8192) {
#pragma unroll
    for (int m = 0; m < 8; ++m) {
      const int rbase = row0 + wr*128 + m*16 + (g << 2);
      const int b = rbase >> 11, s0 = rbase & 2047;
#pragma unroll
      for (int n = 0; n < 4; ++n) {
        const int d = col0 - 8192 + wc*64 + n*16 + crow;  // 0..4095
        short4 hv;
        hv.x = (short)f2bf(acc[m][n][0]);
        hv.y = (short)f2bf(acc[m][n][1]);
        hv.z = (short)f2bf(acc[m][n][2]);
        hv.w = (short)f2bf(acc[m][n][3]);
        *(short4*)(Vt + ((size_t)(b*4096 + d))*2048 + s0) = hv;
      }
    }
    return;
  }

  // ---- epilogue: C/D layout row = 4g+r, col = crow ----
#pragma unroll
  for (int m = 0; m < 8; ++m) {
    const int rbase = row0 + wr*128 + m*16 + (g << 2);
#pragma unroll
    for (int n = 0; n < 4; ++n) {
      const int c = col0 + wc*64 + n*16 + crow;
      bool rot = false;
      float invf = 0.f;
      if (ROPE) {
        rot = (c < 8192) && ((c & 255) < 64);
        if (rot) {
          int i2 = (c & 63) >> 1;
          invf = exp2f(-(float)i2 * 0.4152410118609203f);
        }
      }
#pragma unroll
      for (int r = 0; r < 4; ++r) {
        int rowg = rbase + r;
        float v = acc[m][n][r];
        if (ROPE && rot) {
          float ang = (float)pos[rowg] * invf;
          float s_ = __sinf(ang), c_ = __cosf(ang);
          float pv = __shfl_xor(v, 1, 64);
          v = (c & 1) ? fmaf(v, c_, pv * s_) : fmaf(v, c_, -pv * s_);
        }
        if (OUT_BF16)
          ((unsigned short*)Cp)[(size_t)rowg*N + c] = f2bf(v);
        else
          ((float*)Cp)[(size_t)rowg*N + c] = v;
      }
    }
  }
}

// ---------------- fallback GEMM (round-1): handles f32 operands in-loop -------
template<bool A_BF16, bool ROPE, bool OUT_BF16>
__global__ __launch_bounds__(256)
void gemm128(const void* __restrict__ Ap, const float* __restrict__ Bp,
             const int* __restrict__ pos, void* __restrict__ Cp,
             int N, int K)
{
  __shared__ __align__(16) short Al[128*40];
  __shared__ __align__(16) short Bl[128*40];
  const int tid = threadIdx.x;
  const int lane = tid & 63, wid = tid >> 6;
  const int wr = wid >> 1, wc = wid & 1;
  const int row0 = blockIdx.y * 128, col0 = blockIdx.x * 128;
  f32x4 acc[4][4] = {};
  const int bcol = tid & 127;
  const int kb0 = (tid >> 7) * 4;

  for (int kt = 0; kt < K; kt += 32) {
    if (A_BF16) {
      const unsigned short* Ab = (const unsigned short*)Ap;
      for (int i = 0; i < 2; ++i) {
        int idx = tid + i*256;
        int ar = idx >> 2, ac = (idx & 3) * 8;
        *(int4*)(&Al[ar*40 + ac]) = *(const int4*)(Ab + (size_t)(row0+ar)*K + kt + ac);
      }
    } else {
      const float* Af = (const float*)Ap;
      for (int i = 0; i < 4; ++i) {
        int idx = tid + i*256;
        int ar = idx >> 3, ac = (idx & 7) * 4;
        float4 v = *(const float4*)(Af + (size_t)(row0+ar)*K + kt + ac);
        short4 h;
        h.x = (short)f2bf(v.x); h.y = (short)f2bf(v.y);
        h.z = (short)f2bf(v.z); h.w = (short)f2bf(v.w);
        *(short4*)(&Al[ar*40 + ac]) = h;
      }
    }
    for (int r = 0; r < 4; ++r) {
      int kb = kb0 + r*8;
      const float* bp = Bp + (size_t)(kt+kb)*N + col0 + bcol;
      float x0 = bp[0];
      float x1 = bp[(size_t)N];
      float x2 = bp[2*(size_t)N];
      float x3 = bp[3*(size_t)N];
      short4 h;
      h.x = (short)f2bf(x0); h.y = (short)f2bf(x1);
      h.z = (short)f2bf(x2); h.w = (short)f2bf(x3);
      *(short4*)(&Bl[bcol*40 + kb]) = h;
    }
    __syncthreads();
    const int k8 = (lane >> 4) * 8;
    bf16x8 af[4], bfr[4];
    for (int m = 0; m < 4; ++m)
      af[m] = *(const bf16x8*)(&Al[(wr*64 + m*16 + (lane&15))*40 + k8]);
    for (int n = 0; n < 4; ++n)
      bfr[n] = *(const bf16x8*)(&Bl[(wc*64 + n*16 + (lane&15))*40 + k8]);
    for (int m = 0; m < 4; ++m)
      for (int n = 0; n < 4; ++n)
        acc[m][n] = MFMA_BF16(af[m], bfr[n], acc[m][n]);
    __syncthreads();
  }

  for (int m = 0; m < 4; ++m) {
    const int rbase = row0 + wr*64 + m*16 + ((lane>>4)<<2);
    for (int n = 0; n < 4; ++n) {
      const int c = col0 + wc*64 + n*16 + (lane & 15);
      bool rot = false;
      float invf = 0.f;
      if (ROPE) {
        rot = (c < 8192) && ((c & 255) < 64);
        if (rot) {
          int i2 = (c & 63) >> 1;
          invf = exp2f(-(float)i2 * 0.4152410118609203f);
        }
      }
      for (int r = 0; r < 4; ++r) {
        int rowg = rbase + r;
        float v = acc[m][n][r];
        if (ROPE && rot) {
          float ang = (float)pos[rowg] * invf;
          float s_ = __sinf(ang), c_ = __cosf(ang);
          float pv = __shfl_xor(v, 1, 64);
          v = (c & 1) ? fmaf(v, c_, pv * s_) : fmaf(v, c_, -pv * s_);
        }
        if (OUT_BF16)
          ((unsigned short*)Cp)[(size_t)rowg*N + c] = f2bf(v);
        else
          ((float*)Cp)[(size_t)rowg*N + c] = v;
      }
    }
  }
}

// ---- flash attention v3: 8 waves, QBLK=128, global_load_lds async staging ----
__global__ __launch_bounds__(512, 2)
void attn_kernel3(const unsigned short* __restrict__ qkv,
                  const unsigned short* __restrict__ Vt,
                  unsigned short* __restrict__ ctx)
{
  const int QN = 12288;
  __shared__ __align__(16) unsigned char Kl[2][32768];
  __shared__ __align__(16) unsigned char Vl[2][32768];
  __shared__ __align__(16) unsigned char Pl[128*144];
  const int tid = threadIdx.x, lane = tid & 63, w = tid >> 6;
  const int qp = blockIdx.x, bh = blockIdx.y;
  const int b = bh >> 4, h = bh & 15;
  const size_t rowbase = (size_t)b * 2048;
  const int colr = lane & 15, g = lane >> 4;

  const int kr0 = tid >> 5;
  const int kcolb = ((tid*16) & 511) ^ ((kr0 & 7) << 4);
  const unsigned koff = (unsigned)(kr0*QN) + (kcolb >> 1);
  const int vd0 = tid >> 3;
  const int vcolb = ((tid*16) & 127) ^ ((vd0 & 7) << 4);
  const unsigned voff = (unsigned)(vd0*2048) + (vcolb >> 1);

  const unsigned short* kbase = qkv + rowbase*QN + 4096 + h*256;
  const unsigned short* vbase = Vt + (size_t)bh*256*2048;

#define STAGEKV(KT, B) do {                                                    \
    const unsigned short* kb_ = kbase + (unsigned)(KT)*64u*(unsigned)QN;       \
    const unsigned short* vb_ = vbase + (unsigned)(KT)*64u;                    \
    _Pragma("unroll")                                                          \
    for (int i = 0; i < 4; ++i)                                                \
      GLOAD16(kb_ + koff + i*16*QN, &Kl[B][tid*16 + i*8192]);                  \
    _Pragma("unroll")                                                          \
    for (int i = 0; i < 4; ++i)                                                \
      GLOAD16(vb_ + voff + i*64*2048, &Vl[B][tid*16 + i*8192]);                \
  } while (0)

  for (int phase = 0; phase < 2; ++phase) {
    const int qt = phase ? qp : (15 - qp);
    const int nkt = 2*qt + 2;

    bf16x8 qf[8];
    {
      const unsigned short* qp_ = qkv + (rowbase + qt*128 + w*16 + colr)*QN + h*256 + g*8;
#pragma unroll
      for (int f = 0; f < 8; ++f)
        qf[f] = *(const bf16x8*)(qp_ + 32*f);
    }
    f32x4 acc[16] = {};
    float m_r[4], l_r[4];
#pragma unroll
    for (int r = 0; r < 4; ++r) { m_r[r] = -1e30f; l_r[r] = 0.f; }

    STAGEKV(0, 0);
    STAGEKV(1, 1);
    int cur = 0;

    for (int kt = 0; kt < nkt; ++kt) {
      if (kt < nkt - 1) asm volatile("s_waitcnt vmcnt(8)" ::: "memory");
      else              asm volatile("s_waitcnt vmcnt(0)" ::: "memory");
      __builtin_amdgcn_s_barrier();

      const unsigned char* Kb = Kl[cur];
      f32x4 sc[4];
      __builtin_amdgcn_s_setprio(1);
#pragma unroll
      for (int nf = 0; nf < 4; ++nf) {
        f32x4 s = {};
        int krow = nf*16 + colr;
        int xo2 = (krow & 7) << 4;
        const unsigned char* kp = Kb + krow*512;
#pragma unroll
        for (int st = 0; st < 8; ++st) {
          bf16x8 kf = *(const bf16x8*)(kp + ((64*st + 16*g) ^ xo2));
          s = MFMA_BF16(qf[st], kf, s);
        }
        sc[nf] = s;
      }
      __builtin_amdgcn_s_setprio(0);

      const int qrow0 = qt*128 + w*16 + g*4;
      float pm[4] = {-3e38f,-3e38f,-3e38f,-3e38f};
      float pvv[4][4];
#pragma unroll
      for (int nf = 0; nf < 4; ++nf) {
        int kcol = kt*64 + nf*16 + colr;
#pragma unroll
        for (int r = 0; r < 4; ++r) {
          float v = sc[nf][r] * 0.0625f;
          if (kcol > qrow0 + r) v = -1e30f;
          pvv[nf][r] = v;
          pm[r] = fmaxf(pm[r], v);
        }
      }
#pragma unroll
      for (int mk = 1; mk < 16; mk <<= 1)
#pragma unroll
        for (int r = 0; r < 4; ++r)
          pm[r] = fmaxf(pm[r], __shfl_xor(pm[r], mk, 64));
      float alpha[4];
#pragma unroll
      for (int r = 0; r < 4; ++r) {
        float mn = fmaxf(m_r[r], pm[r]);
        alpha[r] = __expf(m_r[r] - mn);
        m_r[r] = mn;
      }
      float ps[4] = {0.f,0.f,0.f,0.f};
      unsigned short pb[4][4];
#pragma unroll
      for (int nf = 0; nf < 4; ++nf)
#pragma unroll
        for (int r = 0; r < 4; ++r) {
          float p = __expf(pvv[nf][r] - m_r[r]);
          ps[r] += p;
          pb[nf][r] = f2bf(p);
        }
#pragma unroll
      for (int mk = 1; mk < 16; mk <<= 1)
#pragma unroll
        for (int r = 0; r < 4; ++r)
          ps[r] += __shfl_xor(ps[r], mk, 64);
#pragma unroll
      for (int r = 0; r < 4; ++r)
        l_r[r] = l_r[r]*alpha[r] + ps[r];
#pragma unroll
      for (int nf2 = 0; nf2 < 16; ++nf2)
#pragma unroll
        for (int r = 0; r < 4; ++r)
          acc[nf2][r] *= alpha[r];

#pragma unroll
      for (int nf = 0; nf < 4; ++nf)
#pragma unroll
        for (int r = 0; r < 4; ++r)
          *(unsigned short*)(Pl + (w*16 + g*4 + r)*144 + (nf*16 + colr)*2) = pb[nf][r];

      const unsigned char* Vb = Vl[cur];
      __builtin_amdgcn_s_setprio(1);
#pragma unroll
      for (int st2 = 0; st2 < 2; ++st2) {
        bf16x8 pf = *(const bf16x8*)(Pl + (w*16 + colr)*144 + (32*st2 + g*8)*2);
#pragma unroll
        for (int nf2 = 0; nf2 < 16; ++nf2) {
          int d = nf2*16 + colr;
          bf16x8 vf = *(const bf16x8*)(Vb + ((d*128 + 64*st2 + 16*g) ^ ((d&7)<<4)));
          acc[nf2] = MFMA_BF16(pf, vf, acc[nf2]);
        }
      }
      __builtin_amdgcn_s_setprio(0);

      __builtin_amdgcn_sched_barrier(0);
      asm volatile("s_waitcnt lgkmcnt(0)" ::: "memory");
      __builtin_amdgcn_sched_barrier(0);
      __builtin_amdgcn_s_barrier();
      if (kt + 2 < nkt) STAGEKV(kt + 2, cur);
      cur ^= 1;
    }

    float linv[4];
#pragma unroll
    for (int r = 0; r < 4; ++r) linv[r] = 1.0f / l_r[r];
#pragma unroll
    for (int nf2 = 0; nf2 < 16; ++nf2)
#pragma unroll
      for (int r = 0; r < 4; ++r) {
        int qrow = qt*128 + w*16 + g*4 + r;
        float o = acc[nf2][r] * linv[r];
        ctx[(rowbase + qrow)*4096 + h*256 + nf2*16 + colr] = f2bf(o);
      }
  }
#undef STAGEKV
}

// ---------------- fallback attention (round-4) --------------------------------
__global__ __launch_bounds__(256, 2)
void attn_kernel2(const unsigned short* __restrict__ qkv,
                  unsigned short* __restrict__ ctx)
{
  const int S = 2048, D = 256, QN = 12288;
  __shared__ __align__(16) unsigned char Kl[64*512];
  __shared__ __align__(16) unsigned char Vl[256*128];
  __shared__ __align__(16) unsigned char Pl[64*144];
  const int tid = threadIdx.x, lane = tid & 63, w = tid >> 6;
  const int qp = blockIdx.x, bh = blockIdx.y;
  const int b = bh >> 4, h = bh & 15;
  const size_t rowbase = (size_t)b * S;
  const int colr = lane & 15, g = lane >> 4;

  const int kr0 = tid >> 5, c8 = (tid & 31) * 8;
  const unsigned kwb = (unsigned)((kr0*512 + c8*2) ^ ((kr0 & 7) << 4));
  const int dd = (tid >> 2) * 4, kbb = (tid & 3) * 4;

  const unsigned short* kbase0 = qkv + rowbase*QN + 4096 + h*D;
  const unsigned short* vbase0 = qkv + rowbase*QN + 8192 + h*D;

  bf16x8 kreg[8];
  short4 vreg[16];

#define LOADKV(KT) do {                                                        \
    const unsigned short* kb_ = kbase0 + (size_t)(KT)*64*QN;                   \
    _Pragma("unroll")                                                          \
    for (int i = 0; i < 8; ++i)                                                \
      kreg[i] = *(const bf16x8*)(kb_ + (size_t)(kr0 + i*8)*QN + c8);           \
    const unsigned short* vb_ = vbase0 + (size_t)(KT)*64*QN;                   \
    _Pragma("unroll")                                                          \
    for (int r4 = 0; r4 < 4; ++r4) {                                           \
      int kb2 = kbb + 16*r4;                                                   \
      _Pragma("unroll")                                                        \
      for (int j = 0; j < 4; ++j)                                              \
        vreg[r4*4+j] = *(const short4*)(vb_ + (size_t)(kb2+j)*QN + dd);        \
    }                                                                          \
  } while (0)

#define WRITEKV() do {                                                         \
    _Pragma("unroll")                                                          \
    for (int i = 0; i < 8; ++i)                                                \
      *(bf16x8*)(Kl + kwb + i*4096) = kreg[i];                                 \
    _Pragma("unroll")                                                          \
    for (int r4 = 0; r4 < 4; ++r4) {                                           \
      int kb2 = kbb + 16*r4;                                                   \
      short4 v0 = vreg[r4*4+0], v1 = vreg[r4*4+1];                             \
      short4 v2 = vreg[r4*4+2], v3 = vreg[r4*4+3];                             \
      short4 t;                                                                \
      t.x=v0.x; t.y=v1.x; t.z=v2.x; t.w=v3.x;                                  \
      *(short4*)(Vl + (((dd+0)*128 + kb2*2) ^ (((dd+0)&7)<<4))) = t;           \
      t.x=v0.y; t.y=v1.y; t.z=v2.y; t.w=v3.y;                                  \
      *(short4*)(Vl + (((dd+1)*128 + kb2*2) ^ (((dd+1)&7)<<4))) = t;           \
      t.x=v0.z; t.y=v1.z; t.z=v2.z; t.w=v3.z;                                  \
      *(short4*)(Vl + (((dd+2)*128 + kb2*2) ^ (((dd+2)&7)<<4))) = t;           \
      t.x=v0.w; t.y=v1.w; t.z=v2.w; t.w=v3.w;                                  \
      *(short4*)(Vl + (((dd+3)*128 + kb2*2) ^ (((dd+3)&7)<<4))) = t;           \
    }                                                                          \
  } while (0)

  for (int phase = 0; phase < 2; ++phase) {
    const int qt = phase ? qp : (31 - qp);

    bf16x8 qf[8];
    {
      const unsigned short* qp_ = qkv + (rowbase + qt*64 + w*16 + colr)*QN + h*D + g*8;
#pragma unroll
      for (int f = 0; f < 8; ++f)
        qf[f] = *(const bf16x8*)(qp_ + 32*f);
    }
    f32x4 acc[16] = {};
    float m_r[4], l_r[4];
#pragma unroll
    for (int r = 0; r < 4; ++r) { m_r[r] = -1e30f; l_r[r] = 0.f; }

    LOADKV(0);
    WRITEKV();
    __syncthreads();

    for (int kt = 0; kt <= qt; ++kt) {
      if (kt < qt) LOADKV(kt + 1);
      __builtin_amdgcn_sched_barrier(0);

      f32x4 sc[4];
#pragma unroll
      for (int nf = 0; nf < 4; ++nf) {
        f32x4 s = {};
        int krow = nf*16 + colr;
        int xo2 = (krow & 7) << 4;
        const unsigned char* kp = Kl + krow*512;
#pragma unroll
        for (int st = 0; st < 8; ++st) {
          bf16x8 kf = *(const bf16x8*)(kp + ((64*st + 16*g) ^ xo2));
          s = MFMA_BF16(qf[st], kf, s);
        }
        sc[nf] = s;
      }

      const int qrow0 = qt*64 + w*16 + g*4;
      float pm[4] = {-3e38f,-3e38f,-3e38f,-3e38f};
      float pvv[4][4];
#pragma unroll
      for (int nf = 0; nf < 4; ++nf) {
        int kcol = kt*64 + nf*16 + colr;
#pragma unroll
        for (int r = 0; r < 4; ++r) {
          float v = sc[nf][r] * 0.0625f;
          if (kcol > qrow0 + r) v = -1e30f;
          pvv[nf][r] = v;
          pm[r] = fmaxf(pm[r], v);
        }
      }
#pragma unroll
      for (int mk = 1; mk < 16; mk <<= 1)
#pragma unroll
        for (int r = 0; r < 4; ++r)
          pm[r] = fmaxf(pm[r], __shfl_xor(pm[r], mk, 64));
      float alpha[4];
#pragma unroll
      for (int r = 0; r < 4; ++r) {
        float mn = fmaxf(m_r[r], pm[r]);
        alpha[r] = __expf(m_r[r] - mn);
        m_r[r] = mn;
      }
      float ps[4] = {0.f,0.f,0.f,0.f};
      unsigned short pb[4][4];
#pragma unroll
      for (int nf = 0; nf < 4; ++nf)
#pragma unroll
        for (int r = 0; r < 4; ++r) {
          float p = __expf(pvv[nf][r] - m_r[r]);
          ps[r] += p;
          pb[nf][r] = f2bf(p);
        }
#pragma unroll
      for (int mk = 1; mk < 16; mk <<= 1)
#pragma unroll
        for (int r = 0; r < 4; ++r)
          ps[r] += __shfl_xor(ps[r], mk, 64);
#pragma unroll
      for (int r = 0; r < 4; ++r)
        l_r[r] = l_r[r]*alpha[r] + ps[r];
#pragma unroll
      for (int nf2 = 0; nf2 < 16; ++nf2)
#pragma unroll
        for (int r = 0; r < 4; ++r)
          acc[nf2][r] *= alpha[r];

#pragma unroll
      for (int nf = 0; nf < 4; ++nf)
#pragma unroll
        for (int r = 0; r < 4; ++r)
          *(unsigned short*)(Pl + (w*16 + g*4 + r)*144 + (nf*16 + colr)*2) = pb[nf][r];

#pragma unroll
      for (int st2 = 0; st2 < 2; ++st2) {
        bf16x8 pf = *(const bf16x8*)(Pl + (w*16 + colr)*144 + (32*st2 + g*8)*2);
#pragma unroll
        for (int nf2 = 0; nf2 < 16; ++nf2) {
          int d = nf2*16 + colr;
          bf16x8 vf = *(const bf16x8*)(Vl + ((d*128 + 64*st2 + 16*g) ^ ((d&7)<<4)));
          acc[nf2] = MFMA_BF16(pf, vf, acc[nf2]);
        }
      }
      __syncthreads();
      if (kt < qt) {
        WRITEKV();
        __syncthreads();
      }
    }

    float linv[4];
#pragma unroll
    for (int r = 0; r < 4; ++r) linv[r] = 1.0f / l_r[r];
#pragma unroll
    for (int nf2 = 0; nf2 < 16; ++nf2)
#pragma unroll
      for (int r = 0; r < 4; ++r) {
        int qrow = qt*64 + w*16 + g*4 + r;
        float o = acc[nf2][r] * linv[r];
        ctx[(rowbase + qrow)*4096 + h*D + nf2*16 + colr] = f2bf(o);
      }
    if (phase == 0) __syncthreads();
  }
#undef LOADKV
#undef WRITEKV
}

extern "C" void kernel_launch(void* const* d_in, const int* in_sizes, int n_in,
                              void* d_out, int out_size, void* d_ws, size_t ws_size,
                              hipStream_t stream) {
  const int*   pos    = (const int*)d_in[0];
  const float* hidden = (const float*)d_in[1];
  const float* Wqkv   = (const float*)d_in[2];
  const float* Wo     = (const float*)d_in[3];

  const size_t QKV_B  = (size_t)4096 * 12288 * 2;
  const size_t CTX_B  = (size_t)4096 * 4096 * 2;
  const size_t VT_B   = (size_t)32 * 256 * 2048 * 2;
  const size_t WO_B   = (size_t)4096 * 4096 * 2;
  const size_t FAST_NEED = QKV_B + QKV_B + CTX_B;

  if (ws_size >= FAST_NEED) {
    unsigned short* qkv     = (unsigned short*)d_ws;
    unsigned short* WqkvT   = (unsigned short*)((char*)d_ws + QKV_B);
    unsigned short* ctx     = (unsigned short*)((char*)d_ws + QKV_B + CTX_B);
    unsigned short* hiddenB = (unsigned short*)((char*)d_ws + 2*QKV_B);

    const bool vfuse  = ws_size >= FAST_NEED + VT_B;
    const bool wofuse = ws_size >= FAST_NEED + VT_B + WO_B;
    unsigned short* Vt  = vfuse ? (unsigned short*)((char*)d_ws + FAST_NEED)
                                : hiddenB;                         // after GEMM1
    unsigned short* WoT = wofuse ? (unsigned short*)((char*)d_ws + FAST_NEED + VT_B)
                                 : WqkvT;                          // after GEMM1

    prep_merged<<<wofuse ? 18432 : 14336, 256, 0, stream>>>(
        hidden, hiddenB, Wqkv, WqkvT,
        wofuse ? Wo : nullptr, wofuse ? WoT : nullptr);
    if (vfuse)
      gemm256p<true, true, true><<<768, 512, 0, stream>>>(
          hiddenB, WqkvT, pos, qkv, 12288, 4096, 16, Vt);
    else
      gemm256p<true, true, false><<<768, 512, 0, stream>>>(
          hiddenB, WqkvT, pos, qkv, 12288, 4096, 16, nullptr);
    if (!wofuse)
      transpose_convert<<<dim3(64, 64), 256, 0, stream>>>(Wo, WoT, 4096, 4096);
    if (!vfuse)
      transpose_v<<<dim3(32, 4, 32), 256, 0, stream>>>(qkv, Vt);
    attn_kernel3<<<dim3(8, 32), 512, 0, stream>>>(qkv, Vt, ctx);
    gemm256p<false, false, false><<<256, 512, 0, stream>>>(
        ctx, WoT, nullptr, d_out, 4096, 4096, 16, nullptr);
  } else {
    if (ws_size < QKV_B + CTX_B) return;
    unsigned short* qkv = (unsigned short*)d_ws;
    unsigned short* ctx = qkv + (size_t)4096 * 12288;
    gemm128<false, true, true><<<dim3(96, 32), 256, 0, stream>>>(
        hidden, Wqkv, pos, qkv, 12288, 4096);
    attn_kernel2<<<dim3(16, 32), 256, 0, stream>>>(qkv, ctx);
    gemm128<true, false, false><<<dim3(32, 32), 256, 0, stream>>>(
        ctx, Wo, nullptr, d_out, 4096, 4096);
  }
}

// Round 14
// 712.441 us; speedup vs baseline: 1.0207x; 1.0207x over previous
//
#include <hip/hip_runtime.h>
#include <hip/hip_bf16.h>

typedef __bf16 bf16x8 __attribute__((ext_vector_type(8)));
typedef float f32x4 __attribute__((ext_vector_type(4)));

#define MFMA_BF16(a,b,c) __builtin_amdgcn_mfma_f32_16x16x32_bf16(a,b,c,0,0,0)

#define GLOAD16(g, l) __builtin_amdgcn_global_load_lds( \
    (const __attribute__((address_space(1))) unsigned int*)(g), \
    (__attribute__((address_space(3))) unsigned int*)(l), 16, 0, 0)

__device__ __forceinline__ unsigned short f2bf(float f) {
  unsigned u = __builtin_bit_cast(unsigned, f);
  return (unsigned short)((u + 0x7FFFu + ((u >> 16) & 1u)) >> 16);
}

// -- merged pre-pass: hidden convert + Wqkv transpose (+ optional Wo transpose)
__global__ __launch_bounds__(256)
void prep_merged(const float* __restrict__ hidden, unsigned short* __restrict__ hiddenB,
                 const float* __restrict__ Wqkv, unsigned short* __restrict__ WqkvT,
                 const float* __restrict__ Wo, unsigned short* __restrict__ WoT) {
  __shared__ float tl[64][65];
  const int id = blockIdx.x;
  const bool hasWo = (WoT != nullptr);
  if (id < 12288) {
    const int n0 = (id % 192) * 64, k0 = (id / 192) * 64;
    const int K = 4096, N = 12288;
    const int tr = threadIdx.x >> 4;
    const int tc4 = (threadIdx.x & 15) * 4;
    for (int i = 0; i < 4; ++i) {
      int r = tr + i*16;
      float4 v = *(const float4*)(Wqkv + (size_t)(k0 + r)*N + n0 + tc4);
      tl[r][tc4+0] = v.x; tl[r][tc4+1] = v.y;
      tl[r][tc4+2] = v.z; tl[r][tc4+3] = v.w;
    }
    __syncthreads();
    for (int i = 0; i < 4; ++i) {
      int nr = tr + i*16;
      short4 h;
      h.x = (short)f2bf(tl[tc4+0][nr]);
      h.y = (short)f2bf(tl[tc4+1][nr]);
      h.z = (short)f2bf(tl[tc4+2][nr]);
      h.w = (short)f2bf(tl[tc4+3][nr]);
      *(short4*)(WqkvT + (size_t)(n0 + nr)*K + k0 + tc4) = h;
    }
  } else if (hasWo && id < 16384) {
    const int id2 = id - 12288;
    const int n0 = (id2 & 63) * 64, k0 = (id2 >> 6) * 64;
    const int K = 4096, N = 4096;
    const int tr = threadIdx.x >> 4;
    const int tc4 = (threadIdx.x & 15) * 4;
    for (int i = 0; i < 4; ++i) {
      int r = tr + i*16;
      float4 v = *(const float4*)(Wo + (size_t)(k0 + r)*N + n0 + tc4);
      tl[r][tc4+0] = v.x; tl[r][tc4+1] = v.y;
      tl[r][tc4+2] = v.z; tl[r][tc4+3] = v.w;
    }
    __syncthreads();
    for (int i = 0; i < 4; ++i) {
      int nr = tr + i*16;
      short4 h;
      h.x = (short)f2bf(tl[tc4+0][nr]);
      h.y = (short)f2bf(tl[tc4+1][nr]);
      h.z = (short)f2bf(tl[tc4+2][nr]);
      h.w = (short)f2bf(tl[tc4+3][nr]);
      *(short4*)(WoT + (size_t)(n0 + nr)*K + k0 + tc4) = h;
    }
  } else {
    const int cbase = hasWo ? 16384 : 12288;
    const int n8 = 4096*4096/8;
    int i = (id - cbase) * 256 + threadIdx.x;
    const int stride = 2048 * 256;
    for (; i < n8; i += stride) {
      float4 a = ((const float4*)hidden)[i*2];
      float4 b = ((const float4*)hidden)[i*2 + 1];
      short4 h0, h1;
      h0.x = (short)f2bf(a.x); h0.y = (short)f2bf(a.y);
      h0.z = (short)f2bf(a.z); h0.w = (short)f2bf(a.w);
      h1.x = (short)f2bf(b.x); h1.y = (short)f2bf(b.y);
      h1.z = (short)f2bf(b.z); h1.w = (short)f2bf(b.w);
      ((short4*)hiddenB)[i*2] = h0;
      ((short4*)hiddenB)[i*2 + 1] = h1;
    }
  }
}

// ---------------- pre-pass: W [K][N] f32 -> Wt [N][K] bf16 (fallback use) -----
__global__ __launch_bounds__(256)
void transpose_convert(const float* __restrict__ W, unsigned short* __restrict__ Wt,
                       int K, int N) {
  __shared__ float tl[64][65];
  const int k0 = blockIdx.y * 64, n0 = blockIdx.x * 64;
  const int tr = threadIdx.x >> 4;
  const int tc4 = (threadIdx.x & 15) * 4;
  for (int i = 0; i < 4; ++i) {
    int r = tr + i*16;
    float4 v = *(const float4*)(W + (size_t)(k0 + r)*N + n0 + tc4);
    tl[r][tc4+0] = v.x; tl[r][tc4+1] = v.y;
    tl[r][tc4+2] = v.z; tl[r][tc4+3] = v.w;
  }
  __syncthreads();
  for (int i = 0; i < 4; ++i) {
    int nr = tr + i*16;
    short4 h;
    h.x = (short)f2bf(tl[tc4+0][nr]);
    h.y = (short)f2bf(tl[tc4+1][nr]);
    h.z = (short)f2bf(tl[tc4+2][nr]);
    h.w = (short)f2bf(tl[tc4+3][nr]);
    *(short4*)(Wt + (size_t)(n0 + nr)*K + k0 + tc4) = h;
  }
}

// ------- pre-pass: V region of qkv -> Vt[bh][d][s] bf16 (non-vfuse fallback) --
__global__ __launch_bounds__(256)
void transpose_v(const unsigned short* __restrict__ qkv,
                 unsigned short* __restrict__ Vt) {
  __shared__ unsigned short tl[64][68];
  const int bh = blockIdx.z;
  const int s0 = blockIdx.x * 64;
  const int d0 = blockIdx.y * 64;
  const int b = bh >> 4, h = bh & 15;
  const int tr = threadIdx.x >> 4;
  const int tc = (threadIdx.x & 15) * 4;
  const unsigned short* src = qkv + ((size_t)(b*2048 + s0))*12288 + 8192 + h*256 + d0;
  for (int i = 0; i < 4; ++i) {
    int s = tr + i*16;
    *(short4*)&tl[s][tc] = *(const short4*)(src + (size_t)s*12288 + tc);
  }
  __syncthreads();
  unsigned short* dst = Vt + ((size_t)bh*256 + d0)*2048 + s0;
  for (int i = 0; i < 4; ++i) {
    int d = tr + i*16;
    short4 h4;
    h4.x = (short)tl[tc+0][d];
    h4.y = (short)tl[tc+1][d];
    h4.z = (short)tl[tc+2][d];
    h4.w = (short)tl[tc+3][d];
    *(short4*)(dst + (size_t)d*2048 + tc) = h4;
  }
}

// -- 256x256 GEMM, BK=64, 8 waves, 8-phase, SINGLE barrier per phase -----------
// r13 staging map + vmcnt(6) discipline, but phase = {reads -> stages -> MFMA
// (compiler fine-grained lgkmcnt: reads drain UNDER MFMAs) -> lgkm0 -> BAR}.
// Pre-MFMA barrier removed: waves skew within a phase so one wave's ds_reads
// overlap another's MFMAs. Invariant audit: every wave drains its reads
// (lgkm0, "memory"-fenced) before passing the phase barrier, so "stage at
// phase q overwrites region last read at phase <= q-1" is unchanged from r9.
template<bool ROPE, bool OUT_BF16, bool VFUSE>
__global__ __launch_bounds__(512, 2)
void gemm256p(const unsigned short* __restrict__ A,
              const unsigned short* __restrict__ Bt,
              const int* __restrict__ pos,
              void* __restrict__ Cp, int N, int K, int nrow,
              unsigned short* __restrict__ Vt)
{
  __shared__ __align__(16) unsigned short L[2][4][8192];   // 128 KiB
  const int tid = threadIdx.x, lane = tid & 63, w = tid >> 6;
  const int wr = w >> 2, wc = w & 3;
  const int nwg = gridDim.x;
  int wg = blockIdx.x;
  if ((nwg & 7) == 0) wg = (wg & 7) * (nwg >> 3) + (wg >> 3);   // XCD swizzle
  const int by = wg % nrow, bx = wg / nrow;   // column-band major
  const int row0 = by * 256, col0 = bx * 256;

  const int crow = lane & 15, g = lane >> 4;
  const int xo = (crow & 7) << 4;           // read-side XOR (bytes)
  const int rB0 = (wc & 1) * 64;
  const unsigned bo = (unsigned)((tid >> 3) * K + (((tid & 7) ^ ((tid >> 3) & 7)) * 8));
  const int nt = K >> 6;

#define STG_A(T,BUF,H,RLO) do { if ((T) < nt)                                   \
    GLOAD16(A + (unsigned)((row0 + (H)*128 + (RLO))*K) + bo + (unsigned)(T)*64u,\
            &L[BUF][H][(RLO)*64 + tid*8]); } while (0)
#define STG_B(T,BUF,H,RLO) do { if ((T) < nt)                                   \
    GLOAD16(Bt + (unsigned)((col0 + (H)*128 + (RLO))*K) + bo + (unsigned)(T)*64u,\
            &L[BUF][2+(H)][(RLO)*64 + tid*8]); } while (0)

#define RD_ALO(BUF) _Pragma("unroll") for (int m = 0; m < 4; ++m)               \
    _Pragma("unroll") for (int kk = 0; kk < 2; ++kk)                            \
      pAlo[m][kk] = *(const bf16x8*)((const char*)&L[BUF][wr][0] +              \
                     (m*16 + crow)*128 + ((((kk*4+g)<<4)) ^ xo));
#define RD_AHI(BUF) _Pragma("unroll") for (int m = 0; m < 4; ++m)               \
    _Pragma("unroll") for (int kk = 0; kk < 2; ++kk)                            \
      pAhi[m][kk] = *(const bf16x8*)((const char*)&L[BUF][wr][0] +              \
                     (64 + m*16 + crow)*128 + ((((kk*4+g)<<4)) ^ xo));
#define RD_B0(BUF) _Pragma("unroll") for (int n = 0; n < 2; ++n)                \
    _Pragma("unroll") for (int kk = 0; kk < 2; ++kk)                            \
      pB0[n][kk] = *(const bf16x8*)((const char*)&L[BUF][2+(wc>>1)][0] +        \
                    (rB0 + n*16 + crow)*128 + ((((kk*4+g)<<4)) ^ xo));
#define RD_B1(BUF) _Pragma("unroll") for (int n = 0; n < 2; ++n)                \
    _Pragma("unroll") for (int kk = 0; kk < 2; ++kk)                            \
      pB1[n][kk] = *(const bf16x8*)((const char*)&L[BUF][2+(wc>>1)][0] +        \
                    (rB0 + 32 + n*16 + crow)*128 + ((((kk*4+g)<<4)) ^ xo));
#define Q00 _Pragma("unroll") for (int kk = 0; kk < 2; ++kk)                    \
    _Pragma("unroll") for (int m = 0; m < 4; ++m)                               \
    _Pragma("unroll") for (int n = 0; n < 2; ++n)                               \
      acc[m][n] = MFMA_BF16(pAlo[m][kk], pB0[n][kk], acc[m][n]);
#define Q01 _Pragma("unroll") for (int kk = 0; kk < 2; ++kk)                    \
    _Pragma("unroll") for (int m = 0; m < 4; ++m)                               \
    _Pragma("unroll") for (int n = 0; n < 2; ++n)                               \
      acc[m][2+n] = MFMA_BF16(pAlo[m][kk], pB1[n][kk], acc[m][2+n]);
#define Q10 _Pragma("unroll") for (int kk = 0; kk < 2; ++kk)                    \
    _Pragma("unroll") for (int m = 0; m < 4; ++m)                               \
    _Pragma("unroll") for (int n = 0; n < 2; ++n)                               \
      acc[4+m][n] = MFMA_BF16(pAhi[m][kk], pB0[n][kk], acc[4+m][n]);
#define Q11 _Pragma("unroll") for (int kk = 0; kk < 2; ++kk)                    \
    _Pragma("unroll") for (int m = 0; m < 4; ++m)                               \
    _Pragma("unroll") for (int n = 0; n < 2; ++n)                               \
      acc[4+m][2+n] = MFMA_BF16(pAhi[m][kk], pB1[n][kk], acc[4+m][2+n]);
#define BAR __builtin_amdgcn_s_barrier()
#define LGKM0 asm volatile("s_waitcnt lgkmcnt(0)" ::: "memory")
#define PRIO1 __builtin_amdgcn_s_setprio(1)
#define PRIO0 __builtin_amdgcn_s_setprio(0)

  f32x4 acc[8][4] = {};
  // ---- prologue: tile0 complete (8 loads) + tile1 minus A-hi (6 loads) ----
  STG_A(0,0,0,0);  STG_A(0,0,0,64); STG_A(0,0,1,0);  STG_A(0,0,1,64);
  STG_B(0,0,0,0);  STG_B(0,0,0,64); STG_B(0,0,1,0);  STG_B(0,0,1,64);
  STG_A(1,1,0,0);  STG_A(1,1,1,0);
  STG_B(1,1,0,0);  STG_B(1,1,0,64); STG_B(1,1,1,0);  STG_B(1,1,1,64);
  asm volatile("s_waitcnt vmcnt(6)" ::: "memory");   // tile 0 resident
  BAR;

  const int nI = nt >> 1;
  for (int i = 0; i < nI; ++i) {
    const int t = 2*i;
    const bool last = (i == nI - 1);
    bf16x8 pAlo[4][2], pAhi[4][2], pB0[2][2], pB1[2][2];

    // ======== tile t (buf0) ========
    // P1: reads Alo+B0 || stage b1.A-hi(t+1); MFMA Q00 (reads drain under it)
    RD_ALO(0); RD_B0(0);
    STG_A(t+1, 1, 0, 64); STG_A(t+1, 1, 1, 64);
    PRIO1; Q00; PRIO0; LGKM0; BAR;
    // P2: read B1 || stage b0.A-lo(t+2); MFMA Q01
    RD_B1(0);
    STG_A(t+2, 0, 0, 0); STG_A(t+2, 0, 1, 0);
    PRIO1; Q01; PRIO0; LGKM0; BAR;
    // P3: read A-hi || stage b0.B-h0(t+2); MFMA Q10
    RD_AHI(0);
    STG_B(t+2, 0, 0, 0); STG_B(t+2, 0, 0, 64);
    PRIO1; Q10; PRIO0; LGKM0; BAR;
    // P4: stage b0.B-h1(t+2); MFMA Q11; vmcnt(6): tile t+1 complete
    STG_B(t+2, 0, 1, 0); STG_B(t+2, 0, 1, 64);
    PRIO1; Q11; PRIO0;
    if (!last) asm volatile("s_waitcnt vmcnt(6)" ::: "memory");
    else       asm volatile("s_waitcnt vmcnt(0)" ::: "memory");
    BAR;

    // ======== tile t+1 (buf1) ========
    // P5: reads Alo+B0 || stage b0.A-hi(t+2); MFMA Q00
    RD_ALO(1); RD_B0(1);
    STG_A(t+2, 0, 0, 64); STG_A(t+2, 0, 1, 64);
    PRIO1; Q00; PRIO0; LGKM0; BAR;
    // P6: read B1 || stage b1.A-lo(t+3); MFMA Q01
    RD_B1(1);
    STG_A(t+3, 1, 0, 0); STG_A(t+3, 1, 1, 0);
    PRIO1; Q01; PRIO0; LGKM0; BAR;
    // P7: read A-hi || stage b1.B-h0(t+3); MFMA Q10
    RD_AHI(1);
    STG_B(t+3, 1, 0, 0); STG_B(t+3, 1, 0, 64);
    PRIO1; Q10; PRIO0; LGKM0; BAR;
    // P8: stage b1.B-h1(t+3); MFMA Q11; vmcnt(6): tile t+2 complete
    STG_B(t+3, 1, 1, 0); STG_B(t+3, 1, 1, 64);
    PRIO1; Q11; PRIO0;
    if (!last) asm volatile("s_waitcnt vmcnt(6)" ::: "memory");
    else       asm volatile("s_waitcnt vmcnt(0)" ::: "memory");
    BAR;
  }
#undef STG_A
#undef STG_B
#undef RD_ALO
#undef RD_AHI
#undef RD_B0
#undef RD_B1
#undef Q00
#undef Q01
#undef Q10
#undef Q11
#undef BAR
#undef LGKM0
#undef PRIO1
#undef PRIO0

  // ---- fused-Vt epilogue for V-region blocks (block-uniform branch) ----
  if (VFUSE && ROPE && col0 >= 8192) {
#pragma unroll
    for (int m = 0; m < 8; ++m) {
      const int rbase = row0 + wr*128 + m*16 + (g << 2);
      const int b = rbase >> 11, s0 = rbase & 2047;
#pragma unroll
      for (int n = 0; n < 4; ++n) {
        const int d = col0 - 8192 + wc*64 + n*16 + crow;  // 0..4095
        short4 hv;
        hv.x = (short)f2bf(acc[m][n][0]);
        hv.y = (short)f2bf(acc[m][n][1]);
        hv.z = (short)f2bf(acc[m][n][2]);
        hv.w = (short)f2bf(acc[m][n][3]);
        *(short4*)(Vt + ((size_t)(b*4096 + d))*2048 + s0) = hv;
      }
    }
    return;
  }

  // ---- epilogue: C/D layout row = 4g+r, col = crow ----
#pragma unroll
  for (int m = 0; m < 8; ++m) {
    const int rbase = row0 + wr*128 + m*16 + (g << 2);
#pragma unroll
    for (int n = 0; n < 4; ++n) {
      const int c = col0 + wc*64 + n*16 + crow;
      bool rot = false;
      float invf = 0.f;
      if (ROPE) {
        rot = (c < 8192) && ((c & 255) < 64);
        if (rot) {
          int i2 = (c & 63) >> 1;
          invf = exp2f(-(float)i2 * 0.4152410118609203f);
        }
      }
#pragma unroll
      for (int r = 0; r < 4; ++r) {
        int rowg = rbase + r;
        float v = acc[m][n][r];
        if (ROPE && rot) {
          float ang = (float)pos[rowg] * invf;
          float s_ = __sinf(ang), c_ = __cosf(ang);
          float pv = __shfl_xor(v, 1, 64);
          v = (c & 1) ? fmaf(v, c_, pv * s_) : fmaf(v, c_, -pv * s_);
        }
        if (OUT_BF16)
          ((unsigned short*)Cp)[(size_t)rowg*N + c] = f2bf(v);
        else
          ((float*)Cp)[(size_t)rowg*N + c] = v;
      }
    }
  }
}

// ---------------- fallback GEMM (round-1): handles f32 operands in-loop -------
template<bool A_BF16, bool ROPE, bool OUT_BF16>
__global__ __launch_bounds__(256)
void gemm128(const void* __restrict__ Ap, const float* __restrict__ Bp,
             const int* __restrict__ pos, void* __restrict__ Cp,
             int N, int K)
{
  __shared__ __align__(16) short Al[128*40];
  __shared__ __align__(16) short Bl[128*40];
  const int tid = threadIdx.x;
  const int lane = tid & 63, wid = tid >> 6;
  const int wr = wid >> 1, wc = wid & 1;
  const int row0 = blockIdx.y * 128, col0 = blockIdx.x * 128;
  f32x4 acc[4][4] = {};
  const int bcol = tid & 127;
  const int kb0 = (tid >> 7) * 4;

  for (int kt = 0; kt < K; kt += 32) {
    if (A_BF16) {
      const unsigned short* Ab = (const unsigned short*)Ap;
      for (int i = 0; i < 2; ++i) {
        int idx = tid + i*256;
        int ar = idx >> 2, ac = (idx & 3) * 8;
        *(int4*)(&Al[ar*40 + ac]) = *(const int4*)(Ab + (size_t)(row0+ar)*K + kt + ac);
      }
    } else {
      const float* Af = (const float*)Ap;
      for (int i = 0; i < 4; ++i) {
        int idx = tid + i*256;
        int ar = idx >> 3, ac = (idx & 7) * 4;
        float4 v = *(const float4*)(Af + (size_t)(row0+ar)*K + kt + ac);
        short4 h;
        h.x = (short)f2bf(v.x); h.y = (short)f2bf(v.y);
        h.z = (short)f2bf(v.z); h.w = (short)f2bf(v.w);
        *(short4*)(&Al[ar*40 + ac]) = h;
      }
    }
    for (int r = 0; r < 4; ++r) {
      int kb = kb0 + r*8;
      const float* bp = Bp + (size_t)(kt+kb)*N + col0 + bcol;
      float x0 = bp[0];
      float x1 = bp[(size_t)N];
      float x2 = bp[2*(size_t)N];
      float x3 = bp[3*(size_t)N];
      short4 h;
      h.x = (short)f2bf(x0); h.y = (short)f2bf(x1);
      h.z = (short)f2bf(x2); h.w = (short)f2bf(x3);
      *(short4*)(&Bl[bcol*40 + kb]) = h;
    }
    __syncthreads();
    const int k8 = (lane >> 4) * 8;
    bf16x8 af[4], bfr[4];
    for (int m = 0; m < 4; ++m)
      af[m] = *(const bf16x8*)(&Al[(wr*64 + m*16 + (lane&15))*40 + k8]);
    for (int n = 0; n < 4; ++n)
      bfr[n] = *(const bf16x8*)(&Bl[(wc*64 + n*16 + (lane&15))*40 + k8]);
    for (int m = 0; m < 4; ++m)
      for (int n = 0; n < 4; ++n)
        acc[m][n] = MFMA_BF16(af[m], bfr[n], acc[m][n]);
    __syncthreads();
  }

  for (int m = 0; m < 4; ++m) {
    const int rbase = row0 + wr*64 + m*16 + ((lane>>4)<<2);
    for (int n = 0; n < 4; ++n) {
      const int c = col0 + wc*64 + n*16 + (lane & 15);
      bool rot = false;
      float invf = 0.f;
      if (ROPE) {
        rot = (c < 8192) && ((c & 255) < 64);
        if (rot) {
          int i2 = (c & 63) >> 1;
          invf = exp2f(-(float)i2 * 0.4152410118609203f);
        }
      }
      for (int r = 0; r < 4; ++r) {
        int rowg = rbase + r;
        float v = acc[m][n][r];
        if (ROPE && rot) {
          float ang = (float)pos[rowg] * invf;
          float s_ = __sinf(ang), c_ = __cosf(ang);
          float pv = __shfl_xor(v, 1, 64);
          v = (c & 1) ? fmaf(v, c_, pv * s_) : fmaf(v, c_, -pv * s_);
        }
        if (OUT_BF16)
          ((unsigned short*)Cp)[(size_t)rowg*N + c] = f2bf(v);
        else
          ((float*)Cp)[(size_t)rowg*N + c] = v;
      }
    }
  }
}

// ---- flash attention v3: 8 waves, QBLK=128, global_load_lds async staging ----
__global__ __launch_bounds__(512, 2)
void attn_kernel3(const unsigned short* __restrict__ qkv,
                  const unsigned short* __restrict__ Vt,
                  unsigned short* __restrict__ ctx)
{
  const int QN = 12288;
  __shared__ __align__(16) unsigned char Kl[2][32768];
  __shared__ __align__(16) unsigned char Vl[2][32768];
  __shared__ __align__(16) unsigned char Pl[128*144];
  const int tid = threadIdx.x, lane = tid & 63, w = tid >> 6;
  const int qp = blockIdx.x, bh = blockIdx.y;
  const int b = bh >> 4, h = bh & 15;
  const size_t rowbase = (size_t)b * 2048;
  const int colr = lane & 15, g = lane >> 4;

  const int kr0 = tid >> 5;
  const int kcolb = ((tid*16) & 511) ^ ((kr0 & 7) << 4);
  const unsigned koff = (unsigned)(kr0*QN) + (kcolb >> 1);
  const int vd0 = tid >> 3;
  const int vcolb = ((tid*16) & 127) ^ ((vd0 & 7) << 4);
  const unsigned voff = (unsigned)(vd0*2048) + (vcolb >> 1);

  const unsigned short* kbase = qkv + rowbase*QN + 4096 + h*256;
  const unsigned short* vbase = Vt + (size_t)bh*256*2048;

#define STAGEKV(KT, B) do {                                                    \
    const unsigned short* kb_ = kbase + (unsigned)(KT)*64u*(unsigned)QN;       \
    const unsigned short* vb_ = vbase + (unsigned)(KT)*64u;                    \
    _Pragma("unroll")                                                          \
    for (int i = 0; i < 4; ++i)                                                \
      GLOAD16(kb_ + koff + i*16*QN, &Kl[B][tid*16 + i*8192]);                  \
    _Pragma("unroll")                                                          \
    for (int i = 0; i < 4; ++i)                                                \
      GLOAD16(vb_ + voff + i*64*2048, &Vl[B][tid*16 + i*8192]);                \
  } while (0)

  for (int phase = 0; phase < 2; ++phase) {
    const int qt = phase ? qp : (15 - qp);
    const int nkt = 2*qt + 2;

    bf16x8 qf[8];
    {
      const unsigned short* qp_ = qkv + (rowbase + qt*128 + w*16 + colr)*QN + h*256 + g*8;
#pragma unroll
      for (int f = 0; f < 8; ++f)
        qf[f] = *(const bf16x8*)(qp_ + 32*f);
    }
    f32x4 acc[16] = {};
    float m_r[4], l_r[4];
#pragma unroll
    for (int r = 0; r < 4; ++r) { m_r[r] = -1e30f; l_r[r] = 0.f; }

    STAGEKV(0, 0);
    STAGEKV(1, 1);
    int cur = 0;

    for (int kt = 0; kt < nkt; ++kt) {
      if (kt < nkt - 1) asm volatile("s_waitcnt vmcnt(8)" ::: "memory");
      else              asm volatile("s_waitcnt vmcnt(0)" ::: "memory");
      __builtin_amdgcn_s_barrier();

      const unsigned char* Kb = Kl[cur];
      f32x4 sc[4];
      __builtin_amdgcn_s_setprio(1);
#pragma unroll
      for (int nf = 0; nf < 4; ++nf) {
        f32x4 s = {};
        int krow = nf*16 + colr;
        int xo2 = (krow & 7) << 4;
        const unsigned char* kp = Kb + krow*512;
#pragma unroll
        for (int st = 0; st < 8; ++st) {
          bf16x8 kf = *(const bf16x8*)(kp + ((64*st + 16*g) ^ xo2));
          s = MFMA_BF16(qf[st], kf, s);
        }
        sc[nf] = s;
      }
      __builtin_amdgcn_s_setprio(0);

      const int qrow0 = qt*128 + w*16 + g*4;
      float pm[4] = {-3e38f,-3e38f,-3e38f,-3e38f};
      float pvv[4][4];
#pragma unroll
      for (int nf = 0; nf < 4; ++nf) {
        int kcol = kt*64 + nf*16 + colr;
#pragma unroll
        for (int r = 0; r < 4; ++r) {
          float v = sc[nf][r] * 0.0625f;
          if (kcol > qrow0 + r) v = -1e30f;
          pvv[nf][r] = v;
          pm[r] = fmaxf(pm[r], v);
        }
      }
#pragma unroll
      for (int mk = 1; mk < 16; mk <<= 1)
#pragma unroll
        for (int r = 0; r < 4; ++r)
          pm[r] = fmaxf(pm[r], __shfl_xor(pm[r], mk, 64));
      float alpha[4];
#pragma unroll
      for (int r = 0; r < 4; ++r) {
        float mn = fmaxf(m_r[r], pm[r]);
        alpha[r] = __expf(m_r[r] - mn);
        m_r[r] = mn;
      }
      float ps[4] = {0.f,0.f,0.f,0.f};
      unsigned short pb[4][4];
#pragma unroll
      for (int nf = 0; nf < 4; ++nf)
#pragma unroll
        for (int r = 0; r < 4; ++r) {
          float p = __expf(pvv[nf][r] - m_r[r]);
          ps[r] += p;
          pb[nf][r] = f2bf(p);
        }
#pragma unroll
      for (int mk = 1; mk < 16; mk <<= 1)
#pragma unroll
        for (int r = 0; r < 4; ++r)
          ps[r] += __shfl_xor(ps[r], mk, 64);
#pragma unroll
      for (int r = 0; r < 4; ++r)
        l_r[r] = l_r[r]*alpha[r] + ps[r];
#pragma unroll
      for (int nf2 = 0; nf2 < 16; ++nf2)
#pragma unroll
        for (int r = 0; r < 4; ++r)
          acc[nf2][r] *= alpha[r];

#pragma unroll
      for (int nf = 0; nf < 4; ++nf)
#pragma unroll
        for (int r = 0; r < 4; ++r)
          *(unsigned short*)(Pl + (w*16 + g*4 + r)*144 + (nf*16 + colr)*2) = pb[nf][r];

      const unsigned char* Vb = Vl[cur];
      __builtin_amdgcn_s_setprio(1);
#pragma unroll
      for (int st2 = 0; st2 < 2; ++st2) {
        bf16x8 pf = *(const bf16x8*)(Pl + (w*16 + colr)*144 + (32*st2 + g*8)*2);
#pragma unroll
        for (int nf2 = 0; nf2 < 16; ++nf2) {
          int d = nf2*16 + colr;
          bf16x8 vf = *(const bf16x8*)(Vb + ((d*128 + 64*st2 + 16*g) ^ ((d&7)<<4)));
          acc[nf2] = MFMA_BF16(pf, vf, acc[nf2]);
        }
      }
      __builtin_amdgcn_s_setprio(0);

      __builtin_amdgcn_sched_barrier(0);
      asm volatile("s_waitcnt lgkmcnt(0)" ::: "memory");
      __builtin_amdgcn_sched_barrier(0);
      __builtin_amdgcn_s_barrier();
      if (kt + 2 < nkt) STAGEKV(kt + 2, cur);
      cur ^= 1;
    }

    float linv[4];
#pragma unroll
    for (int r = 0; r < 4; ++r) linv[r] = 1.0f / l_r[r];
#pragma unroll
    for (int nf2 = 0; nf2 < 16; ++nf2)
#pragma unroll
      for (int r = 0; r < 4; ++r) {
        int qrow = qt*128 + w*16 + g*4 + r;
        float o = acc[nf2][r] * linv[r];
        ctx[(rowbase + qrow)*4096 + h*256 + nf2*16 + colr] = f2bf(o);
      }
  }
#undef STAGEKV
}

// ---------------- fallback attention (round-4) --------------------------------
__global__ __launch_bounds__(256, 2)
void attn_kernel2(const unsigned short* __restrict__ qkv,
                  unsigned short* __restrict__ ctx)
{
  const int S = 2048, D = 256, QN = 12288;
  __shared__ __align__(16) unsigned char Kl[64*512];
  __shared__ __align__(16) unsigned char Vl[256*128];
  __shared__ __align__(16) unsigned char Pl[64*144];
  const int tid = threadIdx.x, lane = tid & 63, w = tid >> 6;
  const int qp = blockIdx.x, bh = blockIdx.y;
  const int b = bh >> 4, h = bh & 15;
  const size_t rowbase = (size_t)b * S;
  const int colr = lane & 15, g = lane >> 4;

  const int kr0 = tid >> 5, c8 = (tid & 31) * 8;
  const unsigned kwb = (unsigned)((kr0*512 + c8*2) ^ ((kr0 & 7) << 4));
  const int dd = (tid >> 2) * 4, kbb = (tid & 3) * 4;

  const unsigned short* kbase0 = qkv + rowbase*QN + 4096 + h*D;
  const unsigned short* vbase0 = qkv + rowbase*QN + 8192 + h*D;

  bf16x8 kreg[8];
  short4 vreg[16];

#define LOADKV(KT) do {                                                        \
    const unsigned short* kb_ = kbase0 + (size_t)(KT)*64*QN;                   \
    _Pragma("unroll")                                                          \
    for (int i = 0; i < 8; ++i)                                                \
      kreg[i] = *(const bf16x8*)(kb_ + (size_t)(kr0 + i*8)*QN + c8);           \
    const unsigned short* vb_ = vbase0 + (size_t)(KT)*64*QN;                   \
    _Pragma("unroll")                                                          \
    for (int r4 = 0; r4 < 4; ++r4) {                                           \
      int kb2 = kbb + 16*r4;                                                   \
      _Pragma("unroll")                                                        \
      for (int j = 0; j < 4; ++j)                                              \
        vreg[r4*4+j] = *(const short4*)(vb_ + (size_t)(kb2+j)*QN + dd);        \
    }                                                                          \
  } while (0)

#define WRITEKV() do {                                                         \
    _Pragma("unroll")                                                          \
    for (int i = 0; i < 8; ++i)                                                \
      *(bf16x8*)(Kl + kwb + i*4096) = kreg[i];                                 \
    _Pragma("unroll")                                                          \
    for (int r4 = 0; r4 < 4; ++r4) {                                           \
      int kb2 = kbb + 16*r4;                                                   \
      short4 v0 = vreg[r4*4+0], v1 = vreg[r4*4+1];                             \
      short4 v2 = vreg[r4*4+2], v3 = vreg[r4*4+3];                             \
      short4 t;                                                                \
      t.x=v0.x; t.y=v1.x; t.z=v2.x; t.w=v3.x;                                  \
      *(short4*)(Vl + (((dd+0)*128 + kb2*2) ^ (((dd+0)&7)<<4))) = t;           \
      t.x=v0.y; t.y=v1.y; t.z=v2.y; t.w=v3.y;                                  \
      *(short4*)(Vl + (((dd+1)*128 + kb2*2) ^ (((dd+1)&7)<<4))) = t;           \
      t.x=v0.z; t.y=v1.z; t.z=v2.z; t.w=v3.z;                                  \
      *(short4*)(Vl + (((dd+2)*128 + kb2*2) ^ (((dd+2)&7)<<4))) = t;           \
      t.x=v0.w; t.y=v1.w; t.z=v2.w; t.w=v3.w;                                  \
      *(short4*)(Vl + (((dd+3)*128 + kb2*2) ^ (((dd+3)&7)<<4))) = t;           \
    }                                                                          \
  } while (0)

  for (int phase = 0; phase < 2; ++phase) {
    const int qt = phase ? qp : (31 - qp);

    bf16x8 qf[8];
    {
      const unsigned short* qp_ = qkv + (rowbase + qt*64 + w*16 + colr)*QN + h*D + g*8;
#pragma unroll
      for (int f = 0; f < 8; ++f)
        qf[f] = *(const bf16x8*)(qp_ + 32*f);
    }
    f32x4 acc[16] = {};
    float m_r[4], l_r[4];
#pragma unroll
    for (int r = 0; r < 4; ++r) { m_r[r] = -1e30f; l_r[r] = 0.f; }

    LOADKV(0);
    WRITEKV();
    __syncthreads();

    for (int kt = 0; kt <= qt; ++kt) {
      if (kt < qt) LOADKV(kt + 1);
      __builtin_amdgcn_sched_barrier(0);

      f32x4 sc[4];
#pragma unroll
      for (int nf = 0; nf < 4; ++nf) {
        f32x4 s = {};
        int krow = nf*16 + colr;
        int xo2 = (krow & 7) << 4;
        const unsigned char* kp = Kl + krow*512;
#pragma unroll
        for (int st = 0; st < 8; ++st) {
          bf16x8 kf = *(const bf16x8*)(kp + ((64*st + 16*g) ^ xo2));
          s = MFMA_BF16(qf[st], kf, s);
        }
        sc[nf] = s;
      }

      const int qrow0 = qt*64 + w*16 + g*4;
      float pm[4] = {-3e38f,-3e38f,-3e38f,-3e38f};
      float pvv[4][4];
#pragma unroll
      for (int nf = 0; nf < 4; ++nf) {
        int kcol = kt*64 + nf*16 + colr;
#pragma unroll
        for (int r = 0; r < 4; ++r) {
          float v = sc[nf][r] * 0.0625f;
          if (kcol > qrow0 + r) v = -1e30f;
          pvv[nf][r] = v;
          pm[r] = fmaxf(pm[r], v);
        }
      }
#pragma unroll
      for (int mk = 1; mk < 16; mk <<= 1)
#pragma unroll
        for (int r = 0; r < 4; ++r)
          pm[r] = fmaxf(pm[r], __shfl_xor(pm[r], mk, 64));
      float alpha[4];
#pragma unroll
      for (int r = 0; r < 4; ++r) {
        float mn = fmaxf(m_r[r], pm[r]);
        alpha[r] = __expf(m_r[r] - mn);
        m_r[r] = mn;
      }
      float ps[4] = {0.f,0.f,0.f,0.f};
      unsigned short pb[4][4];
#pragma unroll
      for (int nf = 0; nf < 4; ++nf)
#pragma unroll
        for (int r = 0; r < 4; ++r) {
          float p = __expf(pvv[nf][r] - m_r[r]);
          ps[r] += p;
          pb[nf][r] = f2bf(p);
        }
#pragma unroll
      for (int mk = 1; mk < 16; mk <<= 1)
#pragma unroll
        for (int r = 0; r < 4; ++r)
          ps[r] += __shfl_xor(ps[r], mk, 64);
#pragma unroll
      for (int r = 0; r < 4; ++r)
        l_r[r] = l_r[r]*alpha[r] + ps[r];
#pragma unroll
      for (int nf2 = 0; nf2 < 16; ++nf2)
#pragma unroll
        for (int r = 0; r < 4; ++r)
          acc[nf2][r] *= alpha[r];

#pragma unroll
      for (int nf = 0; nf < 4; ++nf)
#pragma unroll
        for (int r = 0; r < 4; ++r)
          *(unsigned short*)(Pl + (w*16 + g*4 + r)*144 + (nf*16 + colr)*2) = pb[nf][r];

#pragma unroll
      for (int st2 = 0; st2 < 2; ++st2) {
        bf16x8 pf = *(const bf16x8*)(Pl + (w*16 + colr)*144 + (32*st2 + g*8)*2);
#pragma unroll
        for (int nf2 = 0; nf2 < 16; ++nf2) {
          int d = nf2*16 + colr;
          bf16x8 vf = *(const bf16x8*)(Vl + ((d*128 + 64*st2 + 16*g) ^ ((d&7)<<4)));
          acc[nf2] = MFMA_BF16(pf, vf, acc[nf2]);
        }
      }
      __syncthreads();
      if (kt < qt) {
        WRITEKV();
        __syncthreads();
      }
    }

    float linv[4];
#pragma unroll
    for (int r = 0; r < 4; ++r) linv[r] = 1.0f / l_r[r];
#pragma unroll
    for (int nf2 = 0; nf2 < 16; ++nf2)
#pragma unroll
      for (int r = 0; r < 4; ++r) {
        int qrow = qt*64 + w*16 + g*4 + r;
        float o = acc[nf2][r] * linv[r];
        ctx[(rowbase + qrow)*4096 + h*D + nf2*16 + colr] = f2bf(o);
      }
    if (phase == 0) __syncthreads();
  }
#undef LOADKV
#undef WRITEKV
}

extern "C" void kernel_launch(void* const* d_in, const int* in_sizes, int n_in,
                              void* d_out, int out_size, void* d_ws, size_t ws_size,
                              hipStream_t stream) {
  const int*   pos    = (const int*)d_in[0];
  const float* hidden = (const float*)d_in[1];
  const float* Wqkv   = (const float*)d_in[2];
  const float* Wo     = (const float*)d_in[3];

  const size_t QKV_B  = (size_t)4096 * 12288 * 2;
  const size_t CTX_B  = (size_t)4096 * 4096 * 2;
  const size_t VT_B   = (size_t)32 * 256 * 2048 * 2;
  const size_t WO_B   = (size_t)4096 * 4096 * 2;
  const size_t FAST_NEED = QKV_B + QKV_B + CTX_B;

  if (ws_size >= FAST_NEED) {
    unsigned short* qkv     = (unsigned short*)d_ws;
    unsigned short* WqkvT   = (unsigned short*)((char*)d_ws + QKV_B);
    unsigned short* ctx     = (unsigned short*)((char*)d_ws + QKV_B + CTX_B);
    unsigned short* hiddenB = (unsigned short*)((char*)d_ws + 2*QKV_B);

    const bool vfuse  = ws_size >= FAST_NEED + VT_B;
    const bool wofuse = ws_size >= FAST_NEED + VT_B + WO_B;
    unsigned short* Vt  = vfuse ? (unsigned short*)((char*)d_ws + FAST_NEED)
                                : hiddenB;                         // after GEMM1
    unsigned short* WoT = wofuse ? (unsigned short*)((char*)d_ws + FAST_NEED + VT_B)
                                 : WqkvT;                          // after GEMM1

    prep_merged<<<wofuse ? 18432 : 14336, 256, 0, stream>>>(
        hidden, hiddenB, Wqkv, WqkvT,
        wofuse ? Wo : nullptr, wofuse ? WoT : nullptr);
    if (vfuse)
      gemm256p<true, true, true><<<768, 512, 0, stream>>>(
          hiddenB, WqkvT, pos, qkv, 12288, 4096, 16, Vt);
    else
      gemm256p<true, true, false><<<768, 512, 0, stream>>>(
          hiddenB, WqkvT, pos, qkv, 12288, 4096, 16, nullptr);
    if (!wofuse)
      transpose_convert<<<dim3(64, 64), 256, 0, stream>>>(Wo, WoT, 4096, 4096);
    if (!vfuse)
      transpose_v<<<dim3(32, 4, 32), 256, 0, stream>>>(qkv, Vt);
    attn_kernel3<<<dim3(8, 32), 512, 0, stream>>>(qkv, Vt, ctx);
    gemm256p<false, false, false><<<256, 512, 0, stream>>>(
        ctx, WoT, nullptr, d_out, 4096, 4096, 16, nullptr);
  } else {
    if (ws_size < QKV_B + CTX_B) return;
    unsigned short* qkv = (unsigned short*)d_ws;
    unsigned short* ctx = qkv + (size_t)4096 * 12288;
    gemm128<false, true, true><<<dim3(96, 32), 256, 0, stream>>>(
        hidden, Wqkv, pos, qkv, 12288, 4096);
    attn_kernel2<<<dim3(16, 32), 256, 0, stream>>>(qkv, ctx);
    gemm128<true, false, false><<<dim3(32, 32), 256, 0, stream>>>(
        ctx, Wo, nullptr, d_out, 4096, 4096);
  }
}

// Round 15
// 712.345 us; speedup vs baseline: 1.0209x; 1.0001x over previous
//
#include <hip/hip_runtime.h>
#include <hip/hip_bf16.h>

typedef __bf16 bf16x8 __attribute__((ext_vector_type(8)));
typedef float f32x4 __attribute__((ext_vector_type(4)));

#define MFMA_BF16(a,b,c) __builtin_amdgcn_mfma_f32_16x16x32_bf16(a,b,c,0,0,0)

#define GLOAD16(g, l) __builtin_amdgcn_global_load_lds( \
    (const __attribute__((address_space(1))) unsigned int*)(g), \
    (__attribute__((address_space(3))) unsigned int*)(l), 16, 0, 0)

__device__ __forceinline__ unsigned short f2bf(float f) {
  unsigned u = __builtin_bit_cast(unsigned, f);
  return (unsigned short)((u + 0x7FFFu + ((u >> 16) & 1u)) >> 16);
}

// -- merged pre-pass: hidden convert + Wqkv transpose (+ optional Wo transpose)
__global__ __launch_bounds__(256)
void prep_merged(const float* __restrict__ hidden, unsigned short* __restrict__ hiddenB,
                 const float* __restrict__ Wqkv, unsigned short* __restrict__ WqkvT,
                 const float* __restrict__ Wo, unsigned short* __restrict__ WoT) {
  __shared__ float tl[64][65];
  const int id = blockIdx.x;
  const bool hasWo = (WoT != nullptr);
  if (id < 12288) {
    const int n0 = (id % 192) * 64, k0 = (id / 192) * 64;
    const int K = 4096, N = 12288;
    const int tr = threadIdx.x >> 4;
    const int tc4 = (threadIdx.x & 15) * 4;
    for (int i = 0; i < 4; ++i) {
      int r = tr + i*16;
      float4 v = *(const float4*)(Wqkv + (size_t)(k0 + r)*N + n0 + tc4);
      tl[r][tc4+0] = v.x; tl[r][tc4+1] = v.y;
      tl[r][tc4+2] = v.z; tl[r][tc4+3] = v.w;
    }
    __syncthreads();
    for (int i = 0; i < 4; ++i) {
      int nr = tr + i*16;
      short4 h;
      h.x = (short)f2bf(tl[tc4+0][nr]);
      h.y = (short)f2bf(tl[tc4+1][nr]);
      h.z = (short)f2bf(tl[tc4+2][nr]);
      h.w = (short)f2bf(tl[tc4+3][nr]);
      *(short4*)(WqkvT + (size_t)(n0 + nr)*K + k0 + tc4) = h;
    }
  } else if (hasWo && id < 16384) {
    const int id2 = id - 12288;
    const int n0 = (id2 & 63) * 64, k0 = (id2 >> 6) * 64;
    const int K = 4096, N = 4096;
    const int tr = threadIdx.x >> 4;
    const int tc4 = (threadIdx.x & 15) * 4;
    for (int i = 0; i < 4; ++i) {
      int r = tr + i*16;
      float4 v = *(const float4*)(Wo + (size_t)(k0 + r)*N + n0 + tc4);
      tl[r][tc4+0] = v.x; tl[r][tc4+1] = v.y;
      tl[r][tc4+2] = v.z; tl[r][tc4+3] = v.w;
    }
    __syncthreads();
    for (int i = 0; i < 4; ++i) {
      int nr = tr + i*16;
      short4 h;
      h.x = (short)f2bf(tl[tc4+0][nr]);
      h.y = (short)f2bf(tl[tc4+1][nr]);
      h.z = (short)f2bf(tl[tc4+2][nr]);
      h.w = (short)f2bf(tl[tc4+3][nr]);
      *(short4*)(WoT + (size_t)(n0 + nr)*K + k0 + tc4) = h;
    }
  } else {
    const int cbase = hasWo ? 16384 : 12288;
    const int n8 = 4096*4096/8;
    int i = (id - cbase) * 256 + threadIdx.x;
    const int stride = 2048 * 256;
    for (; i < n8; i += stride) {
      float4 a = ((const float4*)hidden)[i*2];
      float4 b = ((const float4*)hidden)[i*2 + 1];
      short4 h0, h1;
      h0.x = (short)f2bf(a.x); h0.y = (short)f2bf(a.y);
      h0.z = (short)f2bf(a.z); h0.w = (short)f2bf(a.w);
      h1.x = (short)f2bf(b.x); h1.y = (short)f2bf(b.y);
      h1.z = (short)f2bf(b.z); h1.w = (short)f2bf(b.w);
      ((short4*)hiddenB)[i*2] = h0;
      ((short4*)hiddenB)[i*2 + 1] = h1;
    }
  }
}

// ---------------- pre-pass: W [K][N] f32 -> Wt [N][K] bf16 (fallback use) -----
__global__ __launch_bounds__(256)
void transpose_convert(const float* __restrict__ W, unsigned short* __restrict__ Wt,
                       int K, int N) {
  __shared__ float tl[64][65];
  const int k0 = blockIdx.y * 64, n0 = blockIdx.x * 64;
  const int tr = threadIdx.x >> 4;
  const int tc4 = (threadIdx.x & 15) * 4;
  for (int i = 0; i < 4; ++i) {
    int r = tr + i*16;
    float4 v = *(const float4*)(W + (size_t)(k0 + r)*N + n0 + tc4);
    tl[r][tc4+0] = v.x; tl[r][tc4+1] = v.y;
    tl[r][tc4+2] = v.z; tl[r][tc4+3] = v.w;
  }
  __syncthreads();
  for (int i = 0; i < 4; ++i) {
    int nr = tr + i*16;
    short4 h;
    h.x = (short)f2bf(tl[tc4+0][nr]);
    h.y = (short)f2bf(tl[tc4+1][nr]);
    h.z = (short)f2bf(tl[tc4+2][nr]);
    h.w = (short)f2bf(tl[tc4+3][nr]);
    *(short4*)(Wt + (size_t)(n0 + nr)*K + k0 + tc4) = h;
  }
}

// ------- pre-pass: V region of qkv -> Vt[bh][d][s] bf16 (non-vfuse fallback) --
__global__ __launch_bounds__(256)
void transpose_v(const unsigned short* __restrict__ qkv,
                 unsigned short* __restrict__ Vt) {
  __shared__ unsigned short tl[64][68];
  const int bh = blockIdx.z;
  const int s0 = blockIdx.x * 64;
  const int d0 = blockIdx.y * 64;
  const int b = bh >> 4, h = bh & 15;
  const int tr = threadIdx.x >> 4;
  const int tc = (threadIdx.x & 15) * 4;
  const unsigned short* src = qkv + ((size_t)(b*2048 + s0))*12288 + 8192 + h*256 + d0;
  for (int i = 0; i < 4; ++i) {
    int s = tr + i*16;
    *(short4*)&tl[s][tc] = *(const short4*)(src + (size_t)s*12288 + tc);
  }
  __syncthreads();
  unsigned short* dst = Vt + ((size_t)bh*256 + d0)*2048 + s0;
  for (int i = 0; i < 4; ++i) {
    int d = tr + i*16;
    short4 h4;
    h4.x = (short)tl[tc+0][d];
    h4.y = (short)tl[tc+1][d];
    h4.z = (short)tl[tc+2][d];
    h4.w = (short)tl[tc+3][d];
    *(short4*)(dst + (size_t)d*2048 + tc) = h4;
  }
}

// -- 256x256 GEMM, BK=64, 8 waves, 6-phase (P3+P4 merged), 1 barrier/phase ----
// r14 structure with the redundant P3->P4 (P7->P8) barrier removed: merged
// phase = {RD_AHI || 4 B-stages -> Q10+Q11 -> lgkm0 -> vmcnt(6) -> BAR}.
// Stage-safety: B stages need only P2/P6-end (B1 reads drained); vmcnt(6)
// keeps the 6 newest loads (P2's 2 + merged 4, all t+2) in flight while
// forcing P1's b1.Ahi(t+1) complete -> next tile resident. 6 barriers/2 tiles.
template<bool ROPE, bool OUT_BF16, bool VFUSE>
__global__ __launch_bounds__(512, 2)
void gemm256p(const unsigned short* __restrict__ A,
              const unsigned short* __restrict__ Bt,
              const int* __restrict__ pos,
              void* __restrict__ Cp, int N, int K, int nrow,
              unsigned short* __restrict__ Vt)
{
  __shared__ __align__(16) unsigned short L[2][4][8192];   // 128 KiB
  const int tid = threadIdx.x, lane = tid & 63, w = tid >> 6;
  const int wr = w >> 2, wc = w & 3;
  const int nwg = gridDim.x;
  int wg = blockIdx.x;
  if ((nwg & 7) == 0) wg = (wg & 7) * (nwg >> 3) + (wg >> 3);   // XCD swizzle
  const int by = wg % nrow, bx = wg / nrow;   // column-band major
  const int row0 = by * 256, col0 = bx * 256;

  const int crow = lane & 15, g = lane >> 4;
  const int xo = (crow & 7) << 4;           // read-side XOR (bytes)
  const int rB0 = (wc & 1) * 64;
  const unsigned bo = (unsigned)((tid >> 3) * K + (((tid & 7) ^ ((tid >> 3) & 7)) * 8));
  const int nt = K >> 6;

#define STG_A(T,BUF,H,RLO) do { if ((T) < nt)                                   \
    GLOAD16(A + (unsigned)((row0 + (H)*128 + (RLO))*K) + bo + (unsigned)(T)*64u,\
            &L[BUF][H][(RLO)*64 + tid*8]); } while (0)
#define STG_B(T,BUF,H,RLO) do { if ((T) < nt)                                   \
    GLOAD16(Bt + (unsigned)((col0 + (H)*128 + (RLO))*K) + bo + (unsigned)(T)*64u,\
            &L[BUF][2+(H)][(RLO)*64 + tid*8]); } while (0)

#define RD_ALO(BUF) _Pragma("unroll") for (int m = 0; m < 4; ++m)               \
    _Pragma("unroll") for (int kk = 0; kk < 2; ++kk)                            \
      pAlo[m][kk] = *(const bf16x8*)((const char*)&L[BUF][wr][0] +              \
                     (m*16 + crow)*128 + ((((kk*4+g)<<4)) ^ xo));
#define RD_AHI(BUF) _Pragma("unroll") for (int m = 0; m < 4; ++m)               \
    _Pragma("unroll") for (int kk = 0; kk < 2; ++kk)                            \
      pAhi[m][kk] = *(const bf16x8*)((const char*)&L[BUF][wr][0] +              \
                     (64 + m*16 + crow)*128 + ((((kk*4+g)<<4)) ^ xo));
#define RD_B0(BUF) _Pragma("unroll") for (int n = 0; n < 2; ++n)                \
    _Pragma("unroll") for (int kk = 0; kk < 2; ++kk)                            \
      pB0[n][kk] = *(const bf16x8*)((const char*)&L[BUF][2+(wc>>1)][0] +        \
                    (rB0 + n*16 + crow)*128 + ((((kk*4+g)<<4)) ^ xo));
#define RD_B1(BUF) _Pragma("unroll") for (int n = 0; n < 2; ++n)                \
    _Pragma("unroll") for (int kk = 0; kk < 2; ++kk)                            \
      pB1[n][kk] = *(const bf16x8*)((const char*)&L[BUF][2+(wc>>1)][0] +        \
                    (rB0 + 32 + n*16 + crow)*128 + ((((kk*4+g)<<4)) ^ xo));
#define Q00 _Pragma("unroll") for (int kk = 0; kk < 2; ++kk)                    \
    _Pragma("unroll") for (int m = 0; m < 4; ++m)                               \
    _Pragma("unroll") for (int n = 0; n < 2; ++n)                               \
      acc[m][n] = MFMA_BF16(pAlo[m][kk], pB0[n][kk], acc[m][n]);
#define Q01 _Pragma("unroll") for (int kk = 0; kk < 2; ++kk)                    \
    _Pragma("unroll") for (int m = 0; m < 4; ++m)                               \
    _Pragma("unroll") for (int n = 0; n < 2; ++n)                               \
      acc[m][2+n] = MFMA_BF16(pAlo[m][kk], pB1[n][kk], acc[m][2+n]);
#define Q10 _Pragma("unroll") for (int kk = 0; kk < 2; ++kk)                    \
    _Pragma("unroll") for (int m = 0; m < 4; ++m)                               \
    _Pragma("unroll") for (int n = 0; n < 2; ++n)                               \
      acc[4+m][n] = MFMA_BF16(pAhi[m][kk], pB0[n][kk], acc[4+m][n]);
#define Q11 _Pragma("unroll") for (int kk = 0; kk < 2; ++kk)                    \
    _Pragma("unroll") for (int m = 0; m < 4; ++m)                               \
    _Pragma("unroll") for (int n = 0; n < 2; ++n)                               \
      acc[4+m][2+n] = MFMA_BF16(pAhi[m][kk], pB1[n][kk], acc[4+m][2+n]);
#define BAR __builtin_amdgcn_s_barrier()
#define LGKM0 asm volatile("s_waitcnt lgkmcnt(0)" ::: "memory")
#define PRIO1 __builtin_amdgcn_s_setprio(1)
#define PRIO0 __builtin_amdgcn_s_setprio(0)

  f32x4 acc[8][4] = {};
  // ---- prologue: tile0 complete (8 loads) + tile1 minus A-hi (6 loads) ----
  STG_A(0,0,0,0);  STG_A(0,0,0,64); STG_A(0,0,1,0);  STG_A(0,0,1,64);
  STG_B(0,0,0,0);  STG_B(0,0,0,64); STG_B(0,0,1,0);  STG_B(0,0,1,64);
  STG_A(1,1,0,0);  STG_A(1,1,1,0);
  STG_B(1,1,0,0);  STG_B(1,1,0,64); STG_B(1,1,1,0);  STG_B(1,1,1,64);
  asm volatile("s_waitcnt vmcnt(6)" ::: "memory");   // tile 0 resident
  BAR;

  const int nI = nt >> 1;
  for (int i = 0; i < nI; ++i) {
    const int t = 2*i;
    const bool last = (i == nI - 1);
    bf16x8 pAlo[4][2], pAhi[4][2], pB0[2][2], pB1[2][2];

    // ======== tile t (buf0) ========
    // P1: reads Alo+B0 || stage b1.A-hi(t+1); MFMA Q00
    RD_ALO(0); RD_B0(0);
    STG_A(t+1, 1, 0, 64); STG_A(t+1, 1, 1, 64);
    PRIO1; Q00; PRIO0; LGKM0; BAR;
    // P2: read B1 || stage b0.A-lo(t+2); MFMA Q01
    RD_B1(0);
    STG_A(t+2, 0, 0, 0); STG_A(t+2, 0, 1, 0);
    PRIO1; Q01; PRIO0; LGKM0; BAR;
    // P3 (merged): read A-hi || stage b0.B h0+h1(t+2); MFMA Q10+Q11; vmcnt
    RD_AHI(0);
    STG_B(t+2, 0, 0, 0); STG_B(t+2, 0, 0, 64);
    STG_B(t+2, 0, 1, 0); STG_B(t+2, 0, 1, 64);
    PRIO1; Q10; Q11; PRIO0; LGKM0;
    if (!last) asm volatile("s_waitcnt vmcnt(6)" ::: "memory");
    else       asm volatile("s_waitcnt vmcnt(0)" ::: "memory");
    BAR;

    // ======== tile t+1 (buf1) ========
    // P5: reads Alo+B0 || stage b0.A-hi(t+2); MFMA Q00
    RD_ALO(1); RD_B0(1);
    STG_A(t+2, 0, 0, 64); STG_A(t+2, 0, 1, 64);
    PRIO1; Q00; PRIO0; LGKM0; BAR;
    // P6: read B1 || stage b1.A-lo(t+3); MFMA Q01
    RD_B1(1);
    STG_A(t+3, 1, 0, 0); STG_A(t+3, 1, 1, 0);
    PRIO1; Q01; PRIO0; LGKM0; BAR;
    // P7 (merged): read A-hi || stage b1.B h0+h1(t+3); MFMA Q10+Q11; vmcnt
    RD_AHI(1);
    STG_B(t+3, 1, 0, 0); STG_B(t+3, 1, 0, 64);
    STG_B(t+3, 1, 1, 0); STG_B(t+3, 1, 1, 64);
    PRIO1; Q10; Q11; PRIO0; LGKM0;
    if (!last) asm volatile("s_waitcnt vmcnt(6)" ::: "memory");
    else       asm volatile("s_waitcnt vmcnt(0)" ::: "memory");
    BAR;
  }
#undef STG_A
#undef STG_B
#undef RD_ALO
#undef RD_AHI
#undef RD_B0
#undef RD_B1
#undef Q00
#undef Q01
#undef Q10
#undef Q11
#undef BAR
#undef LGKM0
#undef PRIO1
#undef PRIO0

  // ---- fused-Vt epilogue for V-region blocks (block-uniform branch) ----
  if (VFUSE && ROPE && col0 >= 8192) {
#pragma unroll
    for (int m = 0; m < 8; ++m) {
      const int rbase = row0 + wr*128 + m*16 + (g << 2);
      const int b = rbase >> 11, s0 = rbase & 2047;
#pragma unroll
      for (int n = 0; n < 4; ++n) {
        const int d = col0 - 8192 + wc*64 + n*16 + crow;  // 0..4095
        short4 hv;
        hv.x = (short)f2bf(acc[m][n][0]);
        hv.y = (short)f2bf(acc[m][n][1]);
        hv.z = (short)f2bf(acc[m][n][2]);
        hv.w = (short)f2bf(acc[m][n][3]);
        *(short4*)(Vt + ((size_t)(b*4096 + d))*2048 + s0) = hv;
      }
    }
    return;
  }

  // ---- epilogue: C/D layout row = 4g+r, col = crow ----
#pragma unroll
  for (int m = 0; m < 8; ++m) {
    const int rbase = row0 + wr*128 + m*16 + (g << 2);
#pragma unroll
    for (int n = 0; n < 4; ++n) {
      const int c = col0 + wc*64 + n*16 + crow;
      bool rot = false;
      float invf = 0.f;
      if (ROPE) {
        rot = (c < 8192) && ((c & 255) < 64);
        if (rot) {
          int i2 = (c & 63) >> 1;
          invf = exp2f(-(float)i2 * 0.4152410118609203f);
        }
      }
#pragma unroll
      for (int r = 0; r < 4; ++r) {
        int rowg = rbase + r;
        float v = acc[m][n][r];
        if (ROPE && rot) {
          float ang = (float)pos[rowg] * invf;
          float s_ = __sinf(ang), c_ = __cosf(ang);
          float pv = __shfl_xor(v, 1, 64);
          v = (c & 1) ? fmaf(v, c_, pv * s_) : fmaf(v, c_, -pv * s_);
        }
        if (OUT_BF16)
          ((unsigned short*)Cp)[(size_t)rowg*N + c] = f2bf(v);
        else
          ((float*)Cp)[(size_t)rowg*N + c] = v;
      }
    }
  }
}

// ---------------- fallback GEMM (round-1): handles f32 operands in-loop -------
template<bool A_BF16, bool ROPE, bool OUT_BF16>
__global__ __launch_bounds__(256)
void gemm128(const void* __restrict__ Ap, const float* __restrict__ Bp,
             const int* __restrict__ pos, void* __restrict__ Cp,
             int N, int K)
{
  __shared__ __align__(16) short Al[128*40];
  __shared__ __align__(16) short Bl[128*40];
  const int tid = threadIdx.x;
  const int lane = tid & 63, wid = tid >> 6;
  const int wr = wid >> 1, wc = wid & 1;
  const int row0 = blockIdx.y * 128, col0 = blockIdx.x * 128;
  f32x4 acc[4][4] = {};
  const int bcol = tid & 127;
  const int kb0 = (tid >> 7) * 4;

  for (int kt = 0; kt < K; kt += 32) {
    if (A_BF16) {
      const unsigned short* Ab = (const unsigned short*)Ap;
      for (int i = 0; i < 2; ++i) {
        int idx = tid + i*256;
        int ar = idx >> 2, ac = (idx & 3) * 8;
        *(int4*)(&Al[ar*40 + ac]) = *(const int4*)(Ab + (size_t)(row0+ar)*K + kt + ac);
      }
    } else {
      const float* Af = (const float*)Ap;
      for (int i = 0; i < 4; ++i) {
        int idx = tid + i*256;
        int ar = idx >> 3, ac = (idx & 7) * 4;
        float4 v = *(const float4*)(Af + (size_t)(row0+ar)*K + kt + ac);
        short4 h;
        h.x = (short)f2bf(v.x); h.y = (short)f2bf(v.y);
        h.z = (short)f2bf(v.z); h.w = (short)f2bf(v.w);
        *(short4*)(&Al[ar*40 + ac]) = h;
      }
    }
    for (int r = 0; r < 4; ++r) {
      int kb = kb0 + r*8;
      const float* bp = Bp + (size_t)(kt+kb)*N + col0 + bcol;
      float x0 = bp[0];
      float x1 = bp[(size_t)N];
      float x2 = bp[2*(size_t)N];
      float x3 = bp[3*(size_t)N];
      short4 h;
      h.x = (short)f2bf(x0); h.y = (short)f2bf(x1);
      h.z = (short)f2bf(x2); h.w = (short)f2bf(x3);
      *(short4*)(&Bl[bcol*40 + kb]) = h;
    }
    __syncthreads();
    const int k8 = (lane >> 4) * 8;
    bf16x8 af[4], bfr[4];
    for (int m = 0; m < 4; ++m)
      af[m] = *(const bf16x8*)(&Al[(wr*64 + m*16 + (lane&15))*40 + k8]);
    for (int n = 0; n < 4; ++n)
      bfr[n] = *(const bf16x8*)(&Bl[(wc*64 + n*16 + (lane&15))*40 + k8]);
    for (int m = 0; m < 4; ++m)
      for (int n = 0; n < 4; ++n)
        acc[m][n] = MFMA_BF16(af[m], bfr[n], acc[m][n]);
    __syncthreads();
  }

  for (int m = 0; m < 4; ++m) {
    const int rbase = row0 + wr*64 + m*16 + ((lane>>4)<<2);
    for (int n = 0; n < 4; ++n) {
      const int c = col0 + wc*64 + n*16 + (lane & 15);
      bool rot = false;
      float invf = 0.f;
      if (ROPE) {
        rot = (c < 8192) && ((c & 255) < 64);
        if (rot) {
          int i2 = (c & 63) >> 1;
          invf = exp2f(-(float)i2 * 0.4152410118609203f);
        }
      }
      for (int r = 0; r < 4; ++r) {
        int rowg = rbase + r;
        float v = acc[m][n][r];
        if (ROPE && rot) {
          float ang = (float)pos[rowg] * invf;
          float s_ = __sinf(ang), c_ = __cosf(ang);
          float pv = __shfl_xor(v, 1, 64);
          v = (c & 1) ? fmaf(v, c_, pv * s_) : fmaf(v, c_, -pv * s_);
        }
        if (OUT_BF16)
          ((unsigned short*)Cp)[(size_t)rowg*N + c] = f2bf(v);
        else
          ((float*)Cp)[(size_t)rowg*N + c] = v;
      }
    }
  }
}

// ---- flash attention v3: 8 waves, QBLK=128, global_load_lds async staging ----
__global__ __launch_bounds__(512, 2)
void attn_kernel3(const unsigned short* __restrict__ qkv,
                  const unsigned short* __restrict__ Vt,
                  unsigned short* __restrict__ ctx)
{
  const int QN = 12288;
  __shared__ __align__(16) unsigned char Kl[2][32768];
  __shared__ __align__(16) unsigned char Vl[2][32768];
  __shared__ __align__(16) unsigned char Pl[128*144];
  const int tid = threadIdx.x, lane = tid & 63, w = tid >> 6;
  const int qp = blockIdx.x, bh = blockIdx.y;
  const int b = bh >> 4, h = bh & 15;
  const size_t rowbase = (size_t)b * 2048;
  const int colr = lane & 15, g = lane >> 4;

  const int kr0 = tid >> 5;
  const int kcolb = ((tid*16) & 511) ^ ((kr0 & 7) << 4);
  const unsigned koff = (unsigned)(kr0*QN) + (kcolb >> 1);
  const int vd0 = tid >> 3;
  const int vcolb = ((tid*16) & 127) ^ ((vd0 & 7) << 4);
  const unsigned voff = (unsigned)(vd0*2048) + (vcolb >> 1);

  const unsigned short* kbase = qkv + rowbase*QN + 4096 + h*256;
  const unsigned short* vbase = Vt + (size_t)bh*256*2048;

#define STAGEKV(KT, B) do {                                                    \
    const unsigned short* kb_ = kbase + (unsigned)(KT)*64u*(unsigned)QN;       \
    const unsigned short* vb_ = vbase + (unsigned)(KT)*64u;                    \
    _Pragma("unroll")                                                          \
    for (int i = 0; i < 4; ++i)                                                \
      GLOAD16(kb_ + koff + i*16*QN, &Kl[B][tid*16 + i*8192]);                  \
    _Pragma("unroll")                                                          \
    for (int i = 0; i < 4; ++i)                                                \
      GLOAD16(vb_ + voff + i*64*2048, &Vl[B][tid*16 + i*8192]);                \
  } while (0)

  for (int phase = 0; phase < 2; ++phase) {
    const int qt = phase ? qp : (15 - qp);
    const int nkt = 2*qt + 2;

    bf16x8 qf[8];
    {
      const unsigned short* qp_ = qkv + (rowbase + qt*128 + w*16 + colr)*QN + h*256 + g*8;
#pragma unroll
      for (int f = 0; f < 8; ++f)
        qf[f] = *(const bf16x8*)(qp_ + 32*f);
    }
    f32x4 acc[16] = {};
    float m_r[4], l_r[4];
#pragma unroll
    for (int r = 0; r < 4; ++r) { m_r[r] = -1e30f; l_r[r] = 0.f; }

    STAGEKV(0, 0);
    STAGEKV(1, 1);
    int cur = 0;

    for (int kt = 0; kt < nkt; ++kt) {
      if (kt < nkt - 1) asm volatile("s_waitcnt vmcnt(8)" ::: "memory");
      else              asm volatile("s_waitcnt vmcnt(0)" ::: "memory");
      __builtin_amdgcn_s_barrier();

      const unsigned char* Kb = Kl[cur];
      f32x4 sc[4];
      __builtin_amdgcn_s_setprio(1);
#pragma unroll
      for (int nf = 0; nf < 4; ++nf) {
        f32x4 s = {};
        int krow = nf*16 + colr;
        int xo2 = (krow & 7) << 4;
        const unsigned char* kp = Kb + krow*512;
#pragma unroll
        for (int st = 0; st < 8; ++st) {
          bf16x8 kf = *(const bf16x8*)(kp + ((64*st + 16*g) ^ xo2));
          s = MFMA_BF16(qf[st], kf, s);
        }
        sc[nf] = s;
      }
      __builtin_amdgcn_s_setprio(0);

      const int qrow0 = qt*128 + w*16 + g*4;
      float pm[4] = {-3e38f,-3e38f,-3e38f,-3e38f};
      float pvv[4][4];
#pragma unroll
      for (int nf = 0; nf < 4; ++nf) {
        int kcol = kt*64 + nf*16 + colr;
#pragma unroll
        for (int r = 0; r < 4; ++r) {
          float v = sc[nf][r] * 0.0625f;
          if (kcol > qrow0 + r) v = -1e30f;
          pvv[nf][r] = v;
          pm[r] = fmaxf(pm[r], v);
        }
      }
#pragma unroll
      for (int mk = 1; mk < 16; mk <<= 1)
#pragma unroll
        for (int r = 0; r < 4; ++r)
          pm[r] = fmaxf(pm[r], __shfl_xor(pm[r], mk, 64));
      float alpha[4];
#pragma unroll
      for (int r = 0; r < 4; ++r) {
        float mn = fmaxf(m_r[r], pm[r]);
        alpha[r] = __expf(m_r[r] - mn);
        m_r[r] = mn;
      }
      float ps[4] = {0.f,0.f,0.f,0.f};
      unsigned short pb[4][4];
#pragma unroll
      for (int nf = 0; nf < 4; ++nf)
#pragma unroll
        for (int r = 0; r < 4; ++r) {
          float p = __expf(pvv[nf][r] - m_r[r]);
          ps[r] += p;
          pb[nf][r] = f2bf(p);
        }
#pragma unroll
      for (int mk = 1; mk < 16; mk <<= 1)
#pragma unroll
        for (int r = 0; r < 4; ++r)
          ps[r] += __shfl_xor(ps[r], mk, 64);
#pragma unroll
      for (int r = 0; r < 4; ++r)
        l_r[r] = l_r[r]*alpha[r] + ps[r];
#pragma unroll
      for (int nf2 = 0; nf2 < 16; ++nf2)
#pragma unroll
        for (int r = 0; r < 4; ++r)
          acc[nf2][r] *= alpha[r];

#pragma unroll
      for (int nf = 0; nf < 4; ++nf)
#pragma unroll
        for (int r = 0; r < 4; ++r)
          *(unsigned short*)(Pl + (w*16 + g*4 + r)*144 + (nf*16 + colr)*2) = pb[nf][r];

      const unsigned char* Vb = Vl[cur];
      __builtin_amdgcn_s_setprio(1);
#pragma unroll
      for (int st2 = 0; st2 < 2; ++st2) {
        bf16x8 pf = *(const bf16x8*)(Pl + (w*16 + colr)*144 + (32*st2 + g*8)*2);
#pragma unroll
        for (int nf2 = 0; nf2 < 16; ++nf2) {
          int d = nf2*16 + colr;
          bf16x8 vf = *(const bf16x8*)(Vb + ((d*128 + 64*st2 + 16*g) ^ ((d&7)<<4)));
          acc[nf2] = MFMA_BF16(pf, vf, acc[nf2]);
        }
      }
      __builtin_amdgcn_s_setprio(0);

      __builtin_amdgcn_sched_barrier(0);
      asm volatile("s_waitcnt lgkmcnt(0)" ::: "memory");
      __builtin_amdgcn_sched_barrier(0);
      __builtin_amdgcn_s_barrier();
      if (kt + 2 < nkt) STAGEKV(kt + 2, cur);
      cur ^= 1;
    }

    float linv[4];
#pragma unroll
    for (int r = 0; r < 4; ++r) linv[r] = 1.0f / l_r[r];
#pragma unroll
    for (int nf2 = 0; nf2 < 16; ++nf2)
#pragma unroll
      for (int r = 0; r < 4; ++r) {
        int qrow = qt*128 + w*16 + g*4 + r;
        float o = acc[nf2][r] * linv[r];
        ctx[(rowbase + qrow)*4096 + h*256 + nf2*16 + colr] = f2bf(o);
      }
  }
#undef STAGEKV
}

// ---------------- fallback attention (round-4) --------------------------------
__global__ __launch_bounds__(256, 2)
void attn_kernel2(const unsigned short* __restrict__ qkv,
                  unsigned short* __restrict__ ctx)
{
  const int S = 2048, D = 256, QN = 12288;
  __shared__ __align__(16) unsigned char Kl[64*512];
  __shared__ __align__(16) unsigned char Vl[256*128];
  __shared__ __align__(16) unsigned char Pl[64*144];
  const int tid = threadIdx.x, lane = tid & 63, w = tid >> 6;
  const int qp = blockIdx.x, bh = blockIdx.y;
  const int b = bh >> 4, h = bh & 15;
  const size_t rowbase = (size_t)b * S;
  const int colr = lane & 15, g = lane >> 4;

  const int kr0 = tid >> 5, c8 = (tid & 31) * 8;
  const unsigned kwb = (unsigned)((kr0*512 + c8*2) ^ ((kr0 & 7) << 4));
  const int dd = (tid >> 2) * 4, kbb = (tid & 3) * 4;

  const unsigned short* kbase0 = qkv + rowbase*QN + 4096 + h*D;
  const unsigned short* vbase0 = qkv + rowbase*QN + 8192 + h*D;

  bf16x8 kreg[8];
  short4 vreg[16];

#define LOADKV(KT) do {                                                        \
    const unsigned short* kb_ = kbase0 + (size_t)(KT)*64*QN;                   \
    _Pragma("unroll")                                                          \
    for (int i = 0; i < 8; ++i)                                                \
      kreg[i] = *(const bf16x8*)(kb_ + (size_t)(kr0 + i*8)*QN + c8);           \
    const unsigned short* vb_ = vbase0 + (size_t)(KT)*64*QN;                   \
    _Pragma("unroll")                                                          \
    for (int r4 = 0; r4 < 4; ++r4) {                                           \
      int kb2 = kbb + 16*r4;                                                   \
      _Pragma("unroll")                                                        \
      for (int j = 0; j < 4; ++j)                                              \
        vreg[r4*4+j] = *(const short4*)(vb_ + (size_t)(kb2+j)*QN + dd);        \
    }                                                                          \
  } while (0)

#define WRITEKV() do {                                                         \
    _Pragma("unroll")                                                          \
    for (int i = 0; i < 8; ++i)                                                \
      *(bf16x8*)(Kl + kwb + i*4096) = kreg[i];                                 \
    _Pragma("unroll")                                                          \
    for (int r4 = 0; r4 < 4; ++r4) {                                           \
      int kb2 = kbb + 16*r4;                                                   \
      short4 v0 = vreg[r4*4+0], v1 = vreg[r4*4+1];                             \
      short4 v2 = vreg[r4*4+2], v3 = vreg[r4*4+3];                             \
      short4 t;                                                                \
      t.x=v0.x; t.y=v1.x; t.z=v2.x; t.w=v3.x;                                  \
      *(short4*)(Vl + (((dd+0)*128 + kb2*2) ^ (((dd+0)&7)<<4))) = t;           \
      t.x=v0.y; t.y=v1.y; t.z=v2.y; t.w=v3.y;                                  \
      *(short4*)(Vl + (((dd+1)*128 + kb2*2) ^ (((dd+1)&7)<<4))) = t;           \
      t.x=v0.z; t.y=v1.z; t.z=v2.z; t.w=v3.z;                                  \
      *(short4*)(Vl + (((dd+2)*128 + kb2*2) ^ (((dd+2)&7)<<4))) = t;           \
      t.x=v0.w; t.y=v1.w; t.z=v2.w; t.w=v3.w;                                  \
      *(short4*)(Vl + (((dd+3)*128 + kb2*2) ^ (((dd+3)&7)<<4))) = t;           \
    }                                                                          \
  } while (0)

  for (int phase = 0; phase < 2; ++phase) {
    const int qt = phase ? qp : (31 - qp);

    bf16x8 qf[8];
    {
      const unsigned short* qp_ = qkv + (rowbase + qt*64 + w*16 + colr)*QN + h*D + g*8;
#pragma unroll
      for (int f = 0; f < 8; ++f)
        qf[f] = *(const bf16x8*)(qp_ + 32*f);
    }
    f32x4 acc[16] = {};
    float m_r[4], l_r[4];
#pragma unroll
    for (int r = 0; r < 4; ++r) { m_r[r] = -1e30f; l_r[r] = 0.f; }

    LOADKV(0);
    WRITEKV();
    __syncthreads();

    for (int kt = 0; kt <= qt; ++kt) {
      if (kt < qt) LOADKV(kt + 1);
      __builtin_amdgcn_sched_barrier(0);

      f32x4 sc[4];
#pragma unroll
      for (int nf = 0; nf < 4; ++nf) {
        f32x4 s = {};
        int krow = nf*16 + colr;
        int xo2 = (krow & 7) << 4;
        const unsigned char* kp = Kl + krow*512;
#pragma unroll
        for (int st = 0; st < 8; ++st) {
          bf16x8 kf = *(const bf16x8*)(kp + ((64*st + 16*g) ^ xo2));
          s = MFMA_BF16(qf[st], kf, s);
        }
        sc[nf] = s;
      }

      const int qrow0 = qt*64 + w*16 + g*4;
      float pm[4] = {-3e38f,-3e38f,-3e38f,-3e38f};
      float pvv[4][4];
#pragma unroll
      for (int nf = 0; nf < 4; ++nf) {
        int kcol = kt*64 + nf*16 + colr;
#pragma unroll
        for (int r = 0; r < 4; ++r) {
          float v = sc[nf][r] * 0.0625f;
          if (kcol > qrow0 + r) v = -1e30f;
          pvv[nf][r] = v;
          pm[r] = fmaxf(pm[r], v);
        }
      }
#pragma unroll
      for (int mk = 1; mk < 16; mk <<= 1)
#pragma unroll
        for (int r = 0; r < 4; ++r)
          pm[r] = fmaxf(pm[r], __shfl_xor(pm[r], mk, 64));
      float alpha[4];
#pragma unroll
      for (int r = 0; r < 4; ++r) {
        float mn = fmaxf(m_r[r], pm[r]);
        alpha[r] = __expf(m_r[r] - mn);
        m_r[r] = mn;
      }
      float ps[4] = {0.f,0.f,0.f,0.f};
      unsigned short pb[4][4];
#pragma unroll
      for (int nf = 0; nf < 4; ++nf)
#pragma unroll
        for (int r = 0; r < 4; ++r) {
          float p = __expf(pvv[nf][r] - m_r[r]);
          ps[r] += p;
          pb[nf][r] = f2bf(p);
        }
#pragma unroll
      for (int mk = 1; mk < 16; mk <<= 1)
#pragma unroll
        for (int r = 0; r < 4; ++r)
          ps[r] += __shfl_xor(ps[r], mk, 64);
#pragma unroll
      for (int r = 0; r < 4; ++r)
        l_r[r] = l_r[r]*alpha[r] + ps[r];
#pragma unroll
      for (int nf2 = 0; nf2 < 16; ++nf2)
#pragma unroll
        for (int r = 0; r < 4; ++r)
          acc[nf2][r] *= alpha[r];

#pragma unroll
      for (int nf = 0; nf < 4; ++nf)
#pragma unroll
        for (int r = 0; r < 4; ++r)
          *(unsigned short*)(Pl + (w*16 + g*4 + r)*144 + (nf*16 + colr)*2) = pb[nf][r];

#pragma unroll
      for (int st2 = 0; st2 < 2; ++st2) {
        bf16x8 pf = *(const bf16x8*)(Pl + (w*16 + colr)*144 + (32*st2 + g*8)*2);
#pragma unroll
        for (int nf2 = 0; nf2 < 16; ++nf2) {
          int d = nf2*16 + colr;
          bf16x8 vf = *(const bf16x8*)(Vl + ((d*128 + 64*st2 + 16*g) ^ ((d&7)<<4)));
          acc[nf2] = MFMA_BF16(pf, vf, acc[nf2]);
        }
      }
      __syncthreads();
      if (kt < qt) {
        WRITEKV();
        __syncthreads();
      }
    }

    float linv[4];
#pragma unroll
    for (int r = 0; r < 4; ++r) linv[r] = 1.0f / l_r[r];
#pragma unroll
    for (int nf2 = 0; nf2 < 16; ++nf2)
#pragma unroll
      for (int r = 0; r < 4; ++r) {
        int qrow = qt*64 + w*16 + g*4 + r;
        float o = acc[nf2][r] * linv[r];
        ctx[(rowbase + qrow)*4096 + h*D + nf2*16 + colr] = f2bf(o);
      }
    if (phase == 0) __syncthreads();
  }
#undef LOADKV
#undef WRITEKV
}

extern "C" void kernel_launch(void* const* d_in, const int* in_sizes, int n_in,
                              void* d_out, int out_size, void* d_ws, size_t ws_size,
                              hipStream_t stream) {
  const int*   pos    = (const int*)d_in[0];
  const float* hidden = (const float*)d_in[1];
  const float* Wqkv   = (const float*)d_in[2];
  const float* Wo     = (const float*)d_in[3];

  const size_t QKV_B  = (size_t)4096 * 12288 * 2;
  const size_t CTX_B  = (size_t)4096 * 4096 * 2;
  const size_t VT_B   = (size_t)32 * 256 * 2048 * 2;
  const size_t WO_B   = (size_t)4096 * 4096 * 2;
  const size_t FAST_NEED = QKV_B + QKV_B + CTX_B;

  if (ws_size >= FAST_NEED) {
    unsigned short* qkv     = (unsigned short*)d_ws;
    unsigned short* WqkvT   = (unsigned short*)((char*)d_ws + QKV_B);
    unsigned short* ctx     = (unsigned short*)((char*)d_ws + QKV_B + CTX_B);
    unsigned short* hiddenB = (unsigned short*)((char*)d_ws + 2*QKV_B);

    const bool vfuse  = ws_size >= FAST_NEED + VT_B;
    const bool wofuse = ws_size >= FAST_NEED + VT_B + WO_B;
    unsigned short* Vt  = vfuse ? (unsigned short*)((char*)d_ws + FAST_NEED)
                                : hiddenB;                         // after GEMM1
    unsigned short* WoT = wofuse ? (unsigned short*)((char*)d_ws + FAST_NEED + VT_B)
                                 : WqkvT;                          // after GEMM1

    prep_merged<<<wofuse ? 18432 : 14336, 256, 0, stream>>>(
        hidden, hiddenB, Wqkv, WqkvT,
        wofuse ? Wo : nullptr, wofuse ? WoT : nullptr);
    if (vfuse)
      gemm256p<true, true, true><<<768, 512, 0, stream>>>(
          hiddenB, WqkvT, pos, qkv, 12288, 4096, 16, Vt);
    else
      gemm256p<true, true, false><<<768, 512, 0, stream>>>(
          hiddenB, WqkvT, pos, qkv, 12288, 4096, 16, nullptr);
    if (!wofuse)
      transpose_convert<<<dim3(64, 64), 256, 0, stream>>>(Wo, WoT, 4096, 4096);
    if (!vfuse)
      transpose_v<<<dim3(32, 4, 32), 256, 0, stream>>>(qkv, Vt);
    attn_kernel3<<<dim3(8, 32), 512, 0, stream>>>(qkv, Vt, ctx);
    gemm256p<false, false, false><<<256, 512, 0, stream>>>(
        ctx, WoT, nullptr, d_out, 4096, 4096, 16, nullptr);
  } else {
    if (ws_size < QKV_B + CTX_B) return;
    unsigned short* qkv = (unsigned short*)d_ws;
    unsigned short* ctx = qkv + (size_t)4096 * 12288;
    gemm128<false, true, true><<<dim3(96, 32), 256, 0, stream>>>(
        hidden, Wqkv, pos, qkv, 12288, 4096);
    attn_kernel2<<<dim3(16, 32), 256, 0, stream>>>(qkv, ctx);
    gemm128<true, false, false><<<dim3(32, 32), 256, 0, stream>>>(
        ctx, Wo, nullptr, d_out, 4096, 4096);
  }
}